// Round 4
// baseline (750.024 us; speedup 1.0000x reference)
//
#include <hip/hip_runtime.h>
#include <hip/hip_bf16.h>
#include <math.h>

#define LSEQ 2048
#define NB 4
#define DM 1024
#define ZD 128
#define HD 2048
#define ND 16
#define NEXTD 256
#define EMA_C 64
#define EMA_NCH 32

typedef __bf16 bf16x8 __attribute__((ext_vector_type(8)));
typedef __bf16 bf16x4 __attribute__((ext_vector_type(4)));
typedef float f32x4 __attribute__((ext_vector_type(4)));
typedef float f32x16 __attribute__((ext_vector_type(16)));

__device__ __forceinline__ float sigm(float x){ return 1.0f/(1.0f+expf(-x)); }
__device__ __forceinline__ float silu_(float x){ return x/(1.0f+expf(-x)); }
__device__ __forceinline__ float laplacef(float x){ return 0.5f*(1.0f+erff((x-0.70710678f)*2.5066282746f)); }

__device__ __forceinline__ void load_lds16(const __bf16* g, __bf16* l){
  __builtin_amdgcn_global_load_lds((const __attribute__((address_space(1))) void*)g,
                                   (__attribute__((address_space(3))) void*)l, 16, 0, 0);
}

// ---------------- all three weights fp32 -> bf16, one launch ----------------
__global__ __launch_bounds__(256) void f2b_all(const float4* __restrict__ w0, const float4* __restrict__ w1,
                                               const float4* __restrict__ w2, bf16x4* __restrict__ o0,
                                               bf16x4* __restrict__ o1, bf16x4* __restrict__ o2){
  const int i = blockIdx.x*256 + threadIdx.x;
  const int n0 = 524288, n1 = 1081344, n2 = 524288; // Wv, Wmx, Wh in float4 units
  const float4* src; bf16x4* dst; int k;
  if (i < n0){ src = w0; dst = o0; k = i; }
  else if (i < n0+n1){ src = w1; dst = o1; k = i-n0; }
  else if (i < n0+n1+n2){ src = w2; dst = o2; k = i-n0-n1; }
  else return;
  float4 v = src[k];
  bf16x4 o; o[0]=(__bf16)v.x; o[1]=(__bf16)v.y; o[2]=(__bf16)v.z; o[3]=(__bf16)v.w;
  dst[k] = o;
}

// ---------------- LayerNorm: x is [l][b][d]; xnb written b-major [b][l][d] ----------------
__global__ __launch_bounds__(256) void ln_kernel(const float* __restrict__ x, const float* __restrict__ w,
                                                 const float* __restrict__ b, __bf16* __restrict__ xnb){
  const long row = blockIdx.x;           // l*NB + b
  const int tid = threadIdx.x;
  float4 v = ((const float4*)(x + row*DM))[tid];
  float s = v.x+v.y+v.z+v.w;
  float ss = v.x*v.x+v.y*v.y+v.z*v.z+v.w*v.w;
#pragma unroll
  for (int o=32;o>0;o>>=1){ s += __shfl_down(s,o); ss += __shfl_down(ss,o); }
  __shared__ float red[8];
  __shared__ float mv[2];
  const int wid2 = tid>>6, lane = tid&63;
  if (lane==0){ red[wid2]=s; red[4+wid2]=ss; }
  __syncthreads();
  if (tid==0){
    float ts = red[0]+red[1]+red[2]+red[3];
    float tss = red[4]+red[5]+red[6]+red[7];
    float mean = ts*(1.0f/DM);
    float var = tss*(1.0f/DM) - mean*mean;
    mv[0]=mean; mv[1]=rsqrtf(var + 1e-5f);
  }
  __syncthreads();
  const float mean=mv[0], rs=mv[1];
  float4 wv = ((const float4*)w)[tid];
  float4 bv = ((const float4*)b)[tid];
  bf16x4 ob;
  ob[0]=(__bf16)((v.x-mean)*rs*wv.x+bv.x);
  ob[1]=(__bf16)((v.y-mean)*rs*wv.y+bv.y);
  ob[2]=(__bf16)((v.z-mean)*rs*wv.z+bv.z);
  ob[3]=(__bf16)((v.w-mean)*rs*wv.w+bv.w);
  const long l = row >> 2, bb = row & 3;
  ((bf16x4*)(xnb + (bb*LSEQ + l)*DM))[tid]=ob;
}

// ---------------- EMA parameter precompute: i = d*16+n ----------------
__global__ __launch_bounds__(256) void ema_params_k(const float* __restrict__ de, const float* __restrict__ al,
                                                    const float* __restrict__ be, const float* __restrict__ ga,
                                                    float* __restrict__ qo, float* __restrict__ wo,
                                                    float* __restrict__ qco){
  const int i = blockIdx.x*256 + threadIdx.x;
  const float p = sigm(de[i]);
  const float q = 1.0f - p*sigm(al[i]);
  qo[i] = q;
  wo[i] = p*be[i]*ga[i]*0.25f;
  qco[i] = powf(q, (float)EMA_C);
}

// ---------------- EMA pass A: per-chunk partial end-state (b-major xn) ----------------
__global__ __launch_bounds__(64) void ema_chunk_k(const __bf16* __restrict__ xn, const float* __restrict__ qp,
                                                  float* __restrict__ E){
  const int d = blockIdx.x*64 + threadIdx.x;
  const int j = blockIdx.y, b = blockIdx.z;
  float q[ND], s[ND];
#pragma unroll
  for (int n=0;n<ND;n++){ q[n]=qp[d*ND+n]; s[n]=0.0f; }
  const __bf16* xc = xn + ((long)b*LSEQ + (long)j*EMA_C)*DM + d;
#pragma unroll
  for (int lt=0; lt<EMA_C; lt+=4){
    float xv[4];
#pragma unroll
    for (int u=0;u<4;u++) xv[u] = (float)xc[(long)(lt+u)*DM];
#pragma unroll
    for (int u=0;u<4;u++)
#pragma unroll
      for (int n=0;n<ND;n++) s[n] = fmaf(q[n], s[n], xv[u]);
  }
  float4* Eo = (float4*)(E + (((long)b*EMA_NCH + j)*DM + d)*ND);
#pragma unroll
  for (int n=0;n<4;n++) Eo[n] = make_float4(s[4*n], s[4*n+1], s[4*n+2], s[4*n+3]);
}

// ---------------- EMA pass B: serial scan over chunks ----------------
__global__ __launch_bounds__(256) void ema_scan_k(const float* __restrict__ E, const float* __restrict__ qc,
                                                  float* __restrict__ Sinit){
  const int t = blockIdx.x*256 + threadIdx.x;
  const int b = t >> 14;
  const int rem = t & 16383;
  const float q64 = qc[rem];
  float s = 0.0f;
  const long base = (long)b*EMA_NCH*16384 + rem;
  for (int j=0;j<EMA_NCH;j++){
    const long idx = base + (long)j*16384;
    Sinit[idx] = s;
    s = fmaf(q64, s, E[idx]);
  }
}

// ---------------- EMA pass C: outputs (mx written b-major [b][l][d]) ----------------
__global__ __launch_bounds__(64) void ema_out_k(const __bf16* __restrict__ xn, const float* __restrict__ qp,
                                                const float* __restrict__ wp, const float* __restrict__ omega,
                                                const float* __restrict__ Sinit, __bf16* __restrict__ mx){
  const int d = blockIdx.x*64 + threadIdx.x;
  const int j = blockIdx.y, b = blockIdx.z;
  float q[ND], w[ND], s[ND];
  const float4* Si = (const float4*)(Sinit + (((long)b*EMA_NCH + j)*DM + d)*ND);
#pragma unroll
  for (int n=0;n<4;n++){ float4 v=Si[n]; s[4*n]=v.x; s[4*n+1]=v.y; s[4*n+2]=v.z; s[4*n+3]=v.w; }
#pragma unroll
  for (int n=0;n<ND;n++){ q[n]=qp[d*ND+n]; w[n]=wp[d*ND+n]; }
  const float om = omega[d];
  const long base = (long)b*LSEQ + (long)j*EMA_C;
  const __bf16* xc = xn + base*DM + d;
#pragma unroll
  for (int lt=0; lt<EMA_C; lt+=4){
    float xv[4];
#pragma unroll
    for (int u=0;u<4;u++) xv[u] = (float)xc[(long)(lt+u)*DM];
#pragma unroll
    for (int u=0;u<4;u++){
      float a = 0.0f;
#pragma unroll
      for (int n=0;n<ND;n++){ s[n] = fmaf(q[n], s[n], xv[u]); a = fmaf(w[n], s[n], a); }
      mx[(base + lt + u)*DM + d] = (__bf16)silu_(a + xv[u]*om);
    }
  }
}

// ---------------- rotary extension cols [128,256) of qx/kx (b-major) ----------------
__global__ __launch_bounds__(128) void rot_fill(const float* __restrict__ ra, const float* __restrict__ rb,
                                                __bf16* __restrict__ qx, __bf16* __restrict__ kx){
  const int l = blockIdx.x, i = threadIdx.x;
  const int jf = i & 63;
  const float f = expf((float)jf * (-0.14391156831f));
  const float ang = (float)l * f;
  const float sn = sinf(ang), cs = cosf(ang);
  float qv, kv;
  if (i < 64){ qv = ra[i]*cs - ra[i+64]*sn; kv = rb[i]*cs - rb[i+64]*sn; }
  else       { qv = ra[i]*cs + ra[i-64]*sn; kv = rb[i]*cs + rb[i-64]*sn; }
  const __bf16 qb = (__bf16)qv, kb = (__bf16)kv;
#pragma unroll
  for (int b=0;b<NB;b++){
    const long o = ((long)b*LSEQ + l)*NEXTD + 128 + i;
    qx[o] = qb;
    kx[o] = kb;
  }
}

// ---------------- bf16 GEMM: C = A(M,K) * B(N,K)^T, 32x32x16 MFMA ----------------
// 128x128 tile, 4 waves (2x2), each wave 2x2 frags of 32x32. BK=64.
// MODE: 0=v(silu)->vT direct  1=base split(u/qk/r/hx)  2=laplace->S  3=*r->a3  4=final f32
template<int MODE>
__global__ __launch_bounds__(256) void gemm_bt(
    const __bf16* __restrict__ A, const __bf16* __restrict__ Bw,
    int K, long aBatch, long bBatch, const float* __restrict__ bias,
    void* __restrict__ o0, void* __restrict__ o1, void* __restrict__ o2, void* __restrict__ o3,
    const void* __restrict__ x0, const void* __restrict__ x1, const void* __restrict__ x2)
{
  constexpr int SMEM_BYTES = (MODE==0) ? 35328 : 34816;
  __shared__ __align__(16) char smem_raw[SMEM_BYTES];
  __bf16* As = (__bf16*)smem_raw;
  __bf16* Bs = (__bf16*)(smem_raw + 16384);
  const int tid = threadIdx.x;
  const int lane = tid & 63;
  const int wid = tid >> 6;
  const int bz = blockIdx.z;
  const long m0 = (long)blockIdx.x * 128;
  const long n0 = (long)blockIdx.y * 128;
  const __bf16* Ab = A + (long)bz * aBatch;
  const __bf16* Bb = Bw + (long)bz * bBatch;
  const int wm = wid & 1, wn = wid >> 1;
  const int lrow = lane >> 3;
  const int gchunk = (lane & 7) ^ lrow;
  const int l31 = lane & 31, kh = lane >> 5;

  f32x16 acc[2][2];
#pragma unroll
  for (int i=0;i<2;i++)
#pragma unroll
    for (int j=0;j<2;j++)
#pragma unroll
      for (int r=0;r<16;r++) acc[i][j][r] = 0.0f;

  for (int k0=0;k0<K;k0+=64){
    __syncthreads();
#pragma unroll
    for (int j=0;j<4;j++){
      const int g = j*4 + wid;
      const long ar = m0 + g*8 + lrow;
      load_lds16(Ab + ar*(long)K + (k0 + gchunk*8), &As[g*512]);
      const long br = n0 + g*8 + lrow;
      load_lds16(Bb + br*(long)K + (k0 + gchunk*8), &Bs[g*512]);
    }
    __syncthreads();
#pragma unroll
    for (int s=0;s<4;s++){
      const int qd = s*2 + kh;
      bf16x8 af[2], bfv[2];
#pragma unroll
      for (int i=0;i<2;i++){
        const int rowa = wm*64 + i*32 + l31;
        af[i]  = *(const bf16x8*)&As[rowa*64 + ((qd ^ (rowa&7))<<3)];
        const int rowb = wn*64 + i*32 + l31;
        bfv[i] = *(const bf16x8*)&Bs[rowb*64 + ((qd ^ (rowb&7))<<3)];
      }
#pragma unroll
      for (int i=0;i<2;i++)
#pragma unroll
        for (int j=0;j<2;j++)
          acc[i][j] = __builtin_amdgcn_mfma_f32_32x32x16_bf16(af[i], bfv[j], acc[i][j], 0, 0, 0);
    }
  }

  // ---- epilogue. C/D frag layout: col = l31, row = (r&3)+8*(r>>2)+4*kh ----
  __bf16* st = (__bf16*)smem_raw;      // pitch 136 bf16 (generic)
  __bf16* st2 = (__bf16*)smem_raw;     // pitch 138 bf16 (mode 0, transposed)
  float*  stf = (float*)smem_raw;      // pitch 68 f32 (mode 4)
  const int row = tid >> 1, half = tid & 1;
  const long row_g = m0 + row;

  if (MODE == 0){
    // stage transposed: st2[col][row], then write vT[b][h][l] with b128
    __syncthreads();
#pragma unroll
    for (int i=0;i<2;i++){
#pragma unroll
      for (int j=0;j<2;j++){
        const int tc = wn*64 + j*32 + l31;
        const float bb = bias[n0 + tc];
#pragma unroll
        for (int r=0;r<16;r++){
          const int tr = wm*64 + i*32 + (r&3) + 8*(r>>2) + 4*kh;
          st2[tc*138 + tr] = (__bf16)silu_(acc[i][j][r] + bb);
        }
      }
    }
    __syncthreads();
    const int h = tid >> 1;
    const long b = m0 >> 11, l0 = m0 & 2047;
    __bf16* vT = (__bf16*)o0;
    const long base = (b*HD + n0 + h)*LSEQ + l0 + half*64;
#pragma unroll
    for (int k=0;k<8;k++){
      bf16x8 vv = *(const bf16x8*)&st2[h*138 + half*64 + k*8];
      *(bf16x8*)(vT + base + k*8) = vv;
    }
    return;
  }

  if (MODE == 4){
#pragma unroll
    for (int p=0;p<2;p++){
      __syncthreads();
      if (wn == p){
#pragma unroll
        for (int i=0;i<2;i++){
#pragma unroll
          for (int j=0;j<2;j++){
            const int tc = j*32 + l31;
            const float bb = bias[n0 + p*64 + tc];
#pragma unroll
            for (int r=0;r<16;r++){
              const int tr = wm*64 + i*32 + (r&3) + 8*(r>>2) + 4*kh;
              stf[tr*68 + tc] = acc[i][j][r] + bb;
            }
          }
        }
      }
      __syncthreads();
      const long l = row_g & 2047, b = row_g >> 11;
#pragma unroll
      for (int k=0;k<8;k++){
        f32x4 c4 = *(const f32x4*)&stf[row*68 + half*32 + k*4];
        const long cg = n0 + p*64 + half*32 + k*4;
        const long idx_bm = row_g*DM + cg;          // hx, u (b-major)
        const long idx_io = (l*NB + b)*DM + cg;     // x, out (l-major)
        bf16x4 h4 = *(const bf16x4*)((const __bf16*)x0 + idx_bm);
        bf16x4 u4 = *(const bf16x4*)((const __bf16*)x1 + idx_bm);
        float4 xv = *(const float4*)((const float*)x2 + idx_io);
        float4 o;
        o.x = xv.x + (float)u4[0]*(silu_((float)h4[0]+c4[0]) - xv.x);
        o.y = xv.y + (float)u4[1]*(silu_((float)h4[1]+c4[1]) - xv.y);
        o.z = xv.z + (float)u4[2]*(silu_((float)h4[2]+c4[2]) - xv.z);
        o.w = xv.w + (float)u4[3]*(silu_((float)h4[3]+c4[3]) - xv.w);
        *(float4*)((float*)o0 + idx_io) = o;
      }
    }
    return;
  }

  if (MODE == 1 && n0 == DM){
    // q/k block: two passes (q then k); qx/kx rows are b-major -> contiguous
    const float* qkg = (const float*)x0;
    const float* qkb = (const float*)x1;
    __bf16* qx = (__bf16*)o3;
    __bf16* kx = (__bf16*)x2;
#pragma unroll
    for (int pass=0; pass<2; pass++){
      __syncthreads();
#pragma unroll
      for (int i=0;i<2;i++){
#pragma unroll
        for (int j=0;j<2;j++){
          const int tc = wn*64 + j*32 + l31;     // zi 0..127
          const float bb = bias[DM + tc];
          const float g = pass ? qkg[ZD+tc] : qkg[tc];
          const float be = pass ? qkb[ZD+tc] : qkb[tc];
          const float sc = pass ? 1.0f : (1.0f/LSEQ);
#pragma unroll
          for (int r=0;r<16;r++){
            const int tr = wm*64 + i*32 + (r&3) + 8*(r>>2) + 4*kh;
            const float s = silu_(acc[i][j][r] + bb);
            st[tr*136 + tc] = (__bf16)((s*g + be)*sc);
          }
        }
      }
      __syncthreads();
      __bf16* dst = pass ? kx : qx;
      const long base = row_g*NEXTD + half*64;
#pragma unroll
      for (int k=0;k<8;k++){
        bf16x8 vv = *(const bf16x8*)&st[row*136 + half*64 + k*8];
        *(bf16x8*)(dst + base + k*8) = vv;
      }
    }
    return;
  }

  // generic bf16 tile: stage, then b128 row stores
  __syncthreads();
#pragma unroll
  for (int i=0;i<2;i++){
#pragma unroll
    for (int j=0;j<2;j++){
      const int tc = wn*64 + j*32 + l31;
      const long col = n0 + tc;
      float bb = 0.0f;
      if (MODE==1) bb = bias[col];
#pragma unroll
      for (int r=0;r<16;r++){
        const int tr = wm*64 + i*32 + (r&3) + 8*(r>>2) + 4*kh;
        float c = acc[i][j][r] + bb;
        if (MODE==1){ c = (col < DM) ? sigm(c) : ((col < DM+ZD+HD) ? silu_(c) : c); }
        else if (MODE==2) c = laplacef(c);
        st[tr*136 + tc] = (__bf16)c;
      }
    }
  }
  __syncthreads();

  if (MODE==3){
    const __bf16* rp = (const __bf16*)x0;
    const long base = ((long)bz*LSEQ + row_g)*HD + n0 + half*64;
#pragma unroll
    for (int k=0;k<8;k++){
      bf16x8 vv = *(const bf16x8*)&st[row*136 + half*64 + k*8];
      bf16x8 rv = *(const bf16x8*)(rp + base + k*8);
      bf16x8 ov;
#pragma unroll
      for (int e=0;e<8;e++) ov[e] = (__bf16)((float)vv[e]*(float)rv[e]);
      *(bf16x8*)((__bf16*)o0 + base + k*8) = ov;
    }
  } else {
    __bf16* dst; long ld, coff;
    if (MODE==1){
      if (n0 < DM)            { dst = (__bf16*)o0; ld = DM; coff = n0; }          // u
      else if (n0 < DM+ZD+HD) { dst = (__bf16*)o1; ld = HD; coff = n0-DM-ZD; }    // r
      else                    { dst = (__bf16*)o2; ld = DM; coff = n0-DM-ZD-HD; } // hx
    }
    else { dst = (__bf16*)o0 + (long)bz*LSEQ*LSEQ; ld = LSEQ; coff = n0; }        // MODE 2
    const long base = row_g*ld + coff + half*64;
#pragma unroll
    for (int k=0;k<8;k++){
      bf16x8 vv = *(const bf16x8*)&st[row*136 + half*64 + k*8];
      *(bf16x8*)(dst + base + k*8) = vv;
    }
  }
}

extern "C" void kernel_launch(void* const* d_in, const int* in_sizes, int n_in,
                              void* d_out, int out_size, void* d_ws, size_t ws_size,
                              hipStream_t stream) {
  const float* x      = (const float*)d_in[0];
  const float* edelta = (const float*)d_in[1];
  const float* ealpha = (const float*)d_in[2];
  const float* ebeta  = (const float*)d_in[3];
  const float* egamma = (const float*)d_in[4];
  const float* eomega = (const float*)d_in[5];
  const float* lnw    = (const float*)d_in[6];
  const float* lnb    = (const float*)d_in[7];
  const float* Wv     = (const float*)d_in[8];
  const float* bv     = (const float*)d_in[9];
  const float* Wmx    = (const float*)d_in[10];
  const float* bmx    = (const float*)d_in[11];
  const float* Wh     = (const float*)d_in[12];
  const float* bh     = (const float*)d_in[13];
  const float* qkg    = (const float*)d_in[14];
  const float* qkb    = (const float*)d_in[15];
  const float* ralpha = (const float*)d_in[16];
  const float* rbeta  = (const float*)d_in[17];
  float* out = (float*)d_out;

  char* ws = (char*)d_ws;
  size_t off = 0;
  auto alloc = [&](size_t bytes) -> char* {
    char* p = ws + off; off = (off + bytes + 255) & ~(size_t)255; return p;
  };
  char* p_S    = alloc(33554432);  // S bf16 [b][l][m]
  char* p_xnb  = alloc(16777216);  // xn bf16 [b][l][d]; later aliased by qx(4MB)+kx(4MB)
  char* p_mx   = alloc(16777216);  // mx bf16 [b][l][d]
  char* p_wvb  = alloc(4194304);   // Wv bf16
  char* p_wmxb = alloc(8650752);   // Wmx bf16
  char* p_whb  = alloc(4194304);   // Wh bf16
  char* p_eq   = alloc(65536);     // ema q
  char* p_ew   = alloc(65536);     // ema w'
  char* p_qc   = alloc(65536);     // ema q^C
  char* p_a3   = alloc(33554432);  // a3 bf16 [b][l][h]
  char* p_vT   = alloc(33554432);  // vT bf16 [b][h][l]
  char* p_u    = alloc(16777216);  // u bf16 b-major; EMA aliases: E(8MB)+Sinit(8MB)
  char* p_r    = alloc(33554432);  // r bf16 [b][l][h]
  char* p_hx   = alloc(16777216);  // hx bf16 b-major

  float* p_E  = (float*)p_u;                 // consumed before gemm<1> writes u
  float* p_si = (float*)(p_u + 8388608);

  f2b_all<<<8320, 256, 0, stream>>>((const float4*)Wv, (const float4*)Wmx, (const float4*)Wh,
                                    (bf16x4*)p_wvb, (bf16x4*)p_wmxb, (bf16x4*)p_whb);
  ema_params_k<<<64, 256, 0, stream>>>(edelta, ealpha, ebeta, egamma,
                                       (float*)p_eq, (float*)p_ew, (float*)p_qc);
  ln_kernel<<<8192, 256, 0, stream>>>(x, lnw, lnb, (__bf16*)p_xnb);

  // EMA: exact 3-pass chunked scan
  ema_chunk_k<<<dim3(16,EMA_NCH,4), 64, 0, stream>>>((const __bf16*)p_xnb, (const float*)p_eq, p_E);
  ema_scan_k<<<256, 256, 0, stream>>>(p_E, (const float*)p_qc, p_si);
  ema_out_k<<<dim3(16,EMA_NCH,4), 64, 0, stream>>>((const __bf16*)p_xnb, (const float*)p_eq,
                                                   (const float*)p_ew, eomega, p_si, (__bf16*)p_mx);

  // vT = silu(xn @ Wv^T + bv), transposed write (no separate transpose kernel)
  gemm_bt<0><<<dim3(64,16,1), 256, 0, stream>>>((const __bf16*)p_xnb, (const __bf16*)p_wvb,
      1024, 0, 0, bv, p_vT, nullptr, nullptr, nullptr, nullptr, nullptr, nullptr);

  // base = mx @ Wmx^T + bmx -> u / (qx,kx) / r / hx
  __bf16* qx = (__bf16*)p_xnb;
  __bf16* kx = (__bf16*)(p_xnb + 4194304);
  gemm_bt<1><<<dim3(64,33,1), 256, 0, stream>>>((const __bf16*)p_mx, (const __bf16*)p_wmxb,
      1024, 0, 0, bmx, p_u, p_r, p_hx, qx, qkg, qkb, kx);
  rot_fill<<<LSEQ, 128, 0, stream>>>(ralpha, rbeta, qx, kx);

  // S = laplace(qx @ kx^T)
  __bf16* S = (__bf16*)p_S;
  gemm_bt<2><<<dim3(16,16,4), 256, 0, stream>>>(qx, kx,
      256, (long)LSEQ*NEXTD, (long)LSEQ*NEXTD, nullptr, S, nullptr, nullptr, nullptr,
      nullptr, nullptr, nullptr);

  // a3 = (S @ vT^T) * r
  gemm_bt<3><<<dim3(16,16,4), 256, 0, stream>>>(S, (const __bf16*)p_vT,
      2048, (long)LSEQ*LSEQ, (long)HD*LSEQ, nullptr, p_a3, nullptr, nullptr, nullptr,
      p_r, nullptr, nullptr);

  // out = x + u*(silu(hx + a3 @ Wh^T + bh) - x)
  gemm_bt<4><<<dim3(64,8,1), 256, 0, stream>>>((const __bf16*)p_a3, (const __bf16*)p_whb,
      2048, 0, 0, bh, out, nullptr, nullptr, nullptr, p_hx, p_u, x);
}

// Round 5
// 644.714 us; speedup vs baseline: 1.1633x; 1.1633x over previous
//
#include <hip/hip_runtime.h>
#include <hip/hip_bf16.h>
#include <math.h>

#define LSEQ 2048
#define NB 4
#define DM 1024
#define ZD 128
#define HD 2048
#define ND 16
#define NEXTD 256
#define EMA_C 64
#define EMA_NCH 32

typedef __bf16 bf16x8 __attribute__((ext_vector_type(8)));
typedef __bf16 bf16x4 __attribute__((ext_vector_type(4)));
typedef float f32x4 __attribute__((ext_vector_type(4)));

__device__ __forceinline__ float sigm(float x){ return 1.0f/(1.0f+expf(-x)); }
__device__ __forceinline__ float silu_(float x){ return x/(1.0f+expf(-x)); }
__device__ __forceinline__ float laplacef(float x){ return 0.5f*(1.0f+erff((x-0.70710678f)*2.5066282746f)); }

__device__ __forceinline__ void load_lds16(const __bf16* g, __bf16* l){
  __builtin_amdgcn_global_load_lds((const __attribute__((address_space(1))) void*)g,
                                   (__attribute__((address_space(3))) void*)l, 16, 0, 0);
}

// ---------------- all three weights fp32 -> bf16, one launch ----------------
__global__ __launch_bounds__(256) void f2b_all(const float4* __restrict__ w0, const float4* __restrict__ w1,
                                               const float4* __restrict__ w2, bf16x4* __restrict__ o0,
                                               bf16x4* __restrict__ o1, bf16x4* __restrict__ o2){
  const int i = blockIdx.x*256 + threadIdx.x;
  const int n0 = 524288, n1 = 1081344, n2 = 524288;
  const float4* src; bf16x4* dst; int k;
  if (i < n0){ src = w0; dst = o0; k = i; }
  else if (i < n0+n1){ src = w1; dst = o1; k = i-n0; }
  else if (i < n0+n1+n2){ src = w2; dst = o2; k = i-n0-n1; }
  else return;
  float4 v = src[k];
  bf16x4 o; o[0]=(__bf16)v.x; o[1]=(__bf16)v.y; o[2]=(__bf16)v.z; o[3]=(__bf16)v.w;
  dst[k] = o;
}

// ---------------- LayerNorm: one block per row of 1024 (bf16 out, l-major) ----------------
__global__ __launch_bounds__(256) void ln_kernel(const float* __restrict__ x, const float* __restrict__ w,
                                                 const float* __restrict__ b, __bf16* __restrict__ xnb){
  const long row = blockIdx.x;
  const int tid = threadIdx.x;
  float4 v = ((const float4*)(x + row*DM))[tid];
  float s = v.x+v.y+v.z+v.w;
  float ss = v.x*v.x+v.y*v.y+v.z*v.z+v.w*v.w;
#pragma unroll
  for (int o=32;o>0;o>>=1){ s += __shfl_down(s,o); ss += __shfl_down(ss,o); }
  __shared__ float red[8];
  __shared__ float mv[2];
  const int wid2 = tid>>6, lane = tid&63;
  if (lane==0){ red[wid2]=s; red[4+wid2]=ss; }
  __syncthreads();
  if (tid==0){
    float ts = red[0]+red[1]+red[2]+red[3];
    float tss = red[4]+red[5]+red[6]+red[7];
    float mean = ts*(1.0f/DM);
    float var = tss*(1.0f/DM) - mean*mean;
    mv[0]=mean; mv[1]=rsqrtf(var + 1e-5f);
  }
  __syncthreads();
  const float mean=mv[0], rs=mv[1];
  float4 wv = ((const float4*)w)[tid];
  float4 bv = ((const float4*)b)[tid];
  bf16x4 ob;
  ob[0]=(__bf16)((v.x-mean)*rs*wv.x+bv.x);
  ob[1]=(__bf16)((v.y-mean)*rs*wv.y+bv.y);
  ob[2]=(__bf16)((v.z-mean)*rs*wv.z+bv.z);
  ob[3]=(__bf16)((v.w-mean)*rs*wv.w+bv.w);
  ((bf16x4*)(xnb + row*DM))[tid]=ob;
}

// ---------------- EMA parameter precompute ----------------
__global__ __launch_bounds__(256) void ema_params_k(const float* __restrict__ de, const float* __restrict__ al,
                                                    const float* __restrict__ be, const float* __restrict__ ga,
                                                    float* __restrict__ qo, float* __restrict__ wo,
                                                    float* __restrict__ qco){
  const int i = blockIdx.x*256 + threadIdx.x;
  const float p = sigm(de[i]);
  const float q = 1.0f - p*sigm(al[i]);
  qo[i] = q;
  wo[i] = p*be[i]*ga[i]*0.25f;
  qco[i] = powf(q, (float)EMA_C);
}

// ---------------- EMA pass A ----------------
__global__ __launch_bounds__(64) void ema_chunk_k(const __bf16* __restrict__ xn, const float* __restrict__ qp,
                                                  float* __restrict__ E){
  const int d = blockIdx.x*64 + threadIdx.x;
  const int j = blockIdx.y, b = blockIdx.z;
  float q[ND], s[ND];
#pragma unroll
  for (int n=0;n<ND;n++){ q[n]=qp[d*ND+n]; s[n]=0.0f; }
  const __bf16* xc = xn + (long)b*DM + d + (long)j*EMA_C*(NB*DM);
#pragma unroll
  for (int lt=0; lt<EMA_C; lt+=4){
    float xv[4];
#pragma unroll
    for (int u=0;u<4;u++) xv[u] = (float)xc[(long)(lt+u)*(NB*DM)];
#pragma unroll
    for (int u=0;u<4;u++)
#pragma unroll
      for (int n=0;n<ND;n++) s[n] = fmaf(q[n], s[n], xv[u]);
  }
  float4* Eo = (float4*)(E + (((long)b*EMA_NCH + j)*DM + d)*ND);
#pragma unroll
  for (int n=0;n<4;n++) Eo[n] = make_float4(s[4*n], s[4*n+1], s[4*n+2], s[4*n+3]);
}

// ---------------- EMA pass B ----------------
__global__ __launch_bounds__(256) void ema_scan_k(const float* __restrict__ E, const float* __restrict__ qc,
                                                  float* __restrict__ Sinit){
  const int t = blockIdx.x*256 + threadIdx.x;
  const int b = t >> 14;
  const int rem = t & 16383;
  const float q64 = qc[rem];
  float s = 0.0f;
  const long base = (long)b*EMA_NCH*16384 + rem;
  for (int j=0;j<EMA_NCH;j++){
    const long idx = base + (long)j*16384;
    Sinit[idx] = s;
    s = fmaf(q64, s, E[idx]);
  }
}

// ---------------- EMA pass C ----------------
__global__ __launch_bounds__(64) void ema_out_k(const __bf16* __restrict__ xn, const float* __restrict__ qp,
                                                const float* __restrict__ wp, const float* __restrict__ omega,
                                                const float* __restrict__ Sinit, __bf16* __restrict__ mx){
  const int d = blockIdx.x*64 + threadIdx.x;
  const int j = blockIdx.y, b = blockIdx.z;
  float q[ND], w[ND], s[ND];
  const float4* Si = (const float4*)(Sinit + (((long)b*EMA_NCH + j)*DM + d)*ND);
#pragma unroll
  for (int n=0;n<4;n++){ float4 v=Si[n]; s[4*n]=v.x; s[4*n+1]=v.y; s[4*n+2]=v.z; s[4*n+3]=v.w; }
#pragma unroll
  for (int n=0;n<ND;n++){ q[n]=qp[d*ND+n]; w[n]=wp[d*ND+n]; }
  const float om = omega[d];
  const int l0 = j*EMA_C;
  const __bf16* xc = xn + (long)b*DM + d;
#pragma unroll
  for (int lt=0; lt<EMA_C; lt+=4){
    float xv[4];
#pragma unroll
    for (int u=0;u<4;u++) xv[u] = (float)xc[(long)(l0+lt+u)*(NB*DM)];
#pragma unroll
    for (int u=0;u<4;u++){
      float a = 0.0f;
#pragma unroll
      for (int n=0;n<ND;n++){ s[n] = fmaf(q[n], s[n], xv[u]); a = fmaf(w[n], s[n], a); }
      mx[((long)(l0+lt+u)*NB + b)*DM + d] = (__bf16)silu_(a + xv[u]*om);
    }
  }
}

// ---------------- v (L*B,H) -> vT (B,H,L) ----------------
__global__ __launch_bounds__(256) void transpose_v(const __bf16* __restrict__ v, __bf16* __restrict__ vT){
  __shared__ __bf16 t[64][65];
  const int b = blockIdx.z;
  const int l0 = blockIdx.x*64, h0 = blockIdx.y*64;
  const int tx = threadIdx.x & 63, ty = threadIdx.x >> 6;
  for (int i=ty;i<64;i+=4) t[i][tx] = v[((long)(l0+i)*NB + b)*HD + h0 + tx];
  __syncthreads();
  for (int i=ty;i<64;i+=4) vT[((long)b*HD + h0+i)*LSEQ + l0 + tx] = t[tx][i];
}

// ---------------- rotary extension cols [128,256) of qx/kx (b-major) ----------------
__global__ __launch_bounds__(128) void rot_fill(const float* __restrict__ ra, const float* __restrict__ rb,
                                                __bf16* __restrict__ qx, __bf16* __restrict__ kx){
  const int l = blockIdx.x, i = threadIdx.x;
  const int jf = i & 63;
  const float f = expf((float)jf * (-0.14391156831f));
  const float ang = (float)l * f;
  const float sn = sinf(ang), cs = cosf(ang);
  float qv, kv;
  if (i < 64){ qv = ra[i]*cs - ra[i+64]*sn; kv = rb[i]*cs - rb[i+64]*sn; }
  else       { qv = ra[i]*cs + ra[i-64]*sn; kv = rb[i]*cs + rb[i-64]*sn; }
  const __bf16 qb = (__bf16)qv, kb = (__bf16)kv;
#pragma unroll
  for (int b=0;b<NB;b++){
    const long o = ((long)b*LSEQ + l)*NEXTD + 128 + i;
    qx[o] = qb;
    kx[o] = kb;
  }
}

// ---------------- m97-style bf16 GEMM: C = A(M,K) * B(N,K)^T (16x16x32 MFMA) ----------------
// MODE: 1 = merged [base split (y<33)] + [v GEMM (y>=33, A2/B2/bias2 -> o4)]
//       2=laplace->S  3=*r->a3  4=final f32
template<int MODE>
__global__ __launch_bounds__(256) void gemm_bt(
    const __bf16* __restrict__ A, const __bf16* __restrict__ Bw,
    int K, long aBatch, long bBatch, const float* __restrict__ bias,
    void* __restrict__ o0, void* __restrict__ o1, void* __restrict__ o2, void* __restrict__ o3,
    const void* __restrict__ x0, const void* __restrict__ x1, const void* __restrict__ x2,
    const __bf16* __restrict__ A2, const __bf16* __restrict__ B2,
    const float* __restrict__ bias2, void* __restrict__ o4)
{
  __shared__ __align__(16) char smem_raw[34816];
  __bf16* As = (__bf16*)smem_raw;
  __bf16* Bs = (__bf16*)(smem_raw + 16384);
  const int tid = threadIdx.x;
  const int lane = tid & 63;
  const int wid = tid >> 6;
  const int bz = blockIdx.z;
  const long m0 = (long)blockIdx.x * 128;
  long n0 = (long)blockIdx.y * 128;
  const __bf16* Abase = A;
  const __bf16* Bbase = Bw;
  const float* bias_p = bias;
  bool isv = false;
  if (MODE==1 && blockIdx.y >= 33){
    isv = true;
    n0 = (long)(blockIdx.y - 33) * 128;
    Abase = A2; Bbase = B2; bias_p = bias2;
  }
  const __bf16* Ab = Abase + (long)bz * aBatch;
  const __bf16* Bb = Bbase + (long)bz * bBatch;
  const int wm = wid & 1, wn = wid >> 1;
  const int lrow = lane >> 3;
  const int gchunk = (lane & 7) ^ lrow;

  f32x4 acc[4][4];
#pragma unroll
  for (int i=0;i<4;i++)
#pragma unroll
    for (int j=0;j<4;j++)
#pragma unroll
      for (int r=0;r<4;r++) acc[i][j][r] = 0.0f;

  for (int k0=0;k0<K;k0+=64){
    __syncthreads();
#pragma unroll
    for (int j=0;j<4;j++){
      const int g = j*4 + wid;
      const long ar = m0 + g*8 + lrow;
      load_lds16(Ab + ar*(long)K + (k0 + gchunk*8), &As[g*512]);
      const long br = n0 + g*8 + lrow;
      load_lds16(Bb + br*(long)K + (k0 + gchunk*8), &Bs[g*512]);
    }
    __syncthreads();
#pragma unroll
    for (int ks=0;ks<2;ks++){
      bf16x8 af[4], bfv[4];
      const int qd = (lane>>4) + ks*4;
#pragma unroll
      for (int i=0;i<4;i++){
        const int rowa = wm*64 + i*16 + (lane&15);
        af[i]  = *(const bf16x8*)&As[rowa*64 + ((qd ^ (rowa&7))<<3)];
        const int rowb = wn*64 + i*16 + (lane&15);
        bfv[i] = *(const bf16x8*)&Bs[rowb*64 + ((qd ^ (rowb&7))<<3)];
      }
#pragma unroll
      for (int i=0;i<4;i++)
#pragma unroll
        for (int j=0;j<4;j++)
          acc[i][j] = __builtin_amdgcn_mfma_f32_16x16x32_bf16(af[i], bfv[j], acc[i][j], 0, 0, 0);
    }
  }

  // ---------------- epilogue (C row=(lane>>4)*4+reg, col=lane&15 per frag) ----------------
  __bf16* st = (__bf16*)smem_raw;      // 128 x 136 bf16 (272 B pitch)
  float*  stf = (float*)smem_raw;      // 128 x 68 f32
  const int quad = lane >> 4;
  const int row = tid >> 1, half = tid & 1;
  const long row_g = m0 + row;

  if (MODE == 4){
#pragma unroll
    for (int p=0;p<2;p++){
      __syncthreads();
      if (wn == p){
#pragma unroll
        for (int i=0;i<4;i++){
          const int tr0 = wm*64 + i*16 + quad*4;
#pragma unroll
          for (int j=0;j<4;j++){
            const int tc = j*16 + (lane&15);
            const float bb = bias[n0 + p*64 + tc];
#pragma unroll
            for (int r=0;r<4;r++) stf[(tr0+r)*68 + tc] = acc[i][j][r] + bb;
          }
        }
      }
      __syncthreads();
#pragma unroll
      for (int k=0;k<8;k++){
        f32x4 c4 = *(const f32x4*)&stf[row*68 + half*32 + k*4];
        const long cg = n0 + p*64 + half*32 + k*4;
        const long idx = row_g*DM + cg;
        bf16x4 h4 = *(const bf16x4*)((const __bf16*)x0 + idx);
        bf16x4 u4 = *(const bf16x4*)((const __bf16*)x1 + idx);
        float4 xv = *(const float4*)((const float*)x2 + idx);
        float4 o;
        o.x = xv.x + (float)u4[0]*(silu_((float)h4[0]+c4[0]) - xv.x);
        o.y = xv.y + (float)u4[1]*(silu_((float)h4[1]+c4[1]) - xv.y);
        o.z = xv.z + (float)u4[2]*(silu_((float)h4[2]+c4[2]) - xv.z);
        o.w = xv.w + (float)u4[3]*(silu_((float)h4[3]+c4[3]) - xv.w);
        *(float4*)((float*)o0 + idx) = o;
      }
    }
    return;
  }

  if (MODE == 1 && !isv && n0 == DM){
    // q/k block: two bf16 passes from same accumulators; qx/kx b-major contiguous
    const float* qkg = (const float*)x0;
    const float* qkb = (const float*)x1;
    __bf16* qx = (__bf16*)o3;
    __bf16* kx = (__bf16*)x2;
#pragma unroll
    for (int pass=0; pass<2; pass++){
      __syncthreads();
#pragma unroll
      for (int i=0;i<4;i++){
        const int tr0 = wm*64 + i*16 + quad*4;
#pragma unroll
        for (int j=0;j<4;j++){
          const int tc = wn*64 + j*16 + (lane&15);   // zi 0..127
          const float bb = bias[DM + tc];
          const float g = pass ? qkg[ZD+tc] : qkg[tc];
          const float be = pass ? qkb[ZD+tc] : qkb[tc];
          const float sc = pass ? 1.0f : (1.0f/LSEQ);
#pragma unroll
          for (int r=0;r<4;r++){
            const float s = silu_(acc[i][j][r] + bb);
            st[(tr0+r)*136 + tc] = (__bf16)((s*g + be)*sc);
          }
        }
      }
      __syncthreads();
      __bf16* dst = pass ? kx : qx;
      const long l = row_g >> 2, b = row_g & 3;
      const long base = (b*LSEQ + l)*NEXTD;
#pragma unroll
      for (int k=0;k<8;k++){
        bf16x8 vv = *(const bf16x8*)&st[row*136 + half*64 + k*8];
        *(bf16x8*)(dst + base + half*64 + k*8) = vv;
      }
    }
    return;
  }

  // generic bf16-tile staging
  __syncthreads();
#pragma unroll
  for (int i=0;i<4;i++){
    const int tr0 = wm*64 + i*16 + quad*4;
#pragma unroll
    for (int j=0;j<4;j++){
      const int tc = wn*64 + j*16 + (lane&15);
      const long col = n0 + tc;
      float bb = 0.0f;
      if (MODE==1) bb = bias_p[col];
#pragma unroll
      for (int r=0;r<4;r++){
        float c = acc[i][j][r] + bb;
        if (MODE==1){
          if (isv) c = silu_(c);
          else c = (col < DM) ? sigm(c) : ((col < DM+ZD+HD) ? silu_(c) : c);
        }
        else if (MODE==2) c = laplacef(c);
        st[(tr0+r)*136 + tc] = (__bf16)c;
      }
    }
  }
  __syncthreads();

  if (MODE==3){
    const __bf16* rp = (const __bf16*)x0;
    const long base = (row_g*NB + bz)*HD + n0 + half*64;
#pragma unroll
    for (int k=0;k<8;k++){
      bf16x8 vv = *(const bf16x8*)&st[row*136 + half*64 + k*8];
      bf16x8 rv = *(const bf16x8*)(rp + base + k*8);
      bf16x8 ov;
#pragma unroll
      for (int e=0;e<8;e++) ov[e] = (__bf16)((float)vv[e]*(float)rv[e]);
      *(bf16x8*)((__bf16*)o0 + base + k*8) = ov;
    }
  } else {
    __bf16* dst; long ld, coff;
    if (MODE==1){
      if (isv)                { dst = (__bf16*)o4; ld = HD; coff = n0; }          // v
      else if (n0 < DM)       { dst = (__bf16*)o0; ld = DM; coff = n0; }          // u
      else if (n0 < DM+ZD+HD) { dst = (__bf16*)o1; ld = HD; coff = n0-DM-ZD; }    // r
      else                    { dst = (__bf16*)o2; ld = DM; coff = n0-DM-ZD-HD; } // hx
    }
    else { dst = (__bf16*)o0 + (long)bz*LSEQ*LSEQ; ld = LSEQ; coff = n0; }        // MODE 2
    const long base = row_g*ld + coff + half*64;
#pragma unroll
    for (int k=0;k<8;k++){
      bf16x8 vv = *(const bf16x8*)&st[row*136 + half*64 + k*8];
      *(bf16x8*)(dst + base + k*8) = vv;
    }
  }
}

extern "C" void kernel_launch(void* const* d_in, const int* in_sizes, int n_in,
                              void* d_out, int out_size, void* d_ws, size_t ws_size,
                              hipStream_t stream) {
  const float* x      = (const float*)d_in[0];
  const float* edelta = (const float*)d_in[1];
  const float* ealpha = (const float*)d_in[2];
  const float* ebeta  = (const float*)d_in[3];
  const float* egamma = (const float*)d_in[4];
  const float* eomega = (const float*)d_in[5];
  const float* lnw    = (const float*)d_in[6];
  const float* lnb    = (const float*)d_in[7];
  const float* Wv     = (const float*)d_in[8];
  const float* bv     = (const float*)d_in[9];
  const float* Wmx    = (const float*)d_in[10];
  const float* bmx    = (const float*)d_in[11];
  const float* Wh     = (const float*)d_in[12];
  const float* bh     = (const float*)d_in[13];
  const float* qkg    = (const float*)d_in[14];
  const float* qkb    = (const float*)d_in[15];
  const float* ralpha = (const float*)d_in[16];
  const float* rbeta  = (const float*)d_in[17];
  float* out = (float*)d_out;

  char* ws = (char*)d_ws;
  size_t off = 0;
  auto alloc = [&](size_t bytes) -> char* {
    char* p = ws + off; off = (off + bytes + 255) & ~(size_t)255; return p;
  };
  char* p_S    = alloc(33554432);  // S bf16 (4x2048x2048)
  char* p_xnb  = alloc(16777216);  // xn bf16 [l][b][d]
  char* p_qx   = alloc(4194304);   // qx bf16 [b][l][256]
  char* p_kx   = alloc(4194304);   // kx bf16 [b][l][256]
  char* p_mx   = alloc(16777216);  // mx bf16 [l][b][d]
  char* p_wvb  = alloc(4194304);
  char* p_wmxb = alloc(8650752);
  char* p_whb  = alloc(4194304);
  char* p_eq   = alloc(65536);
  char* p_ew   = alloc(65536);
  char* p_qc   = alloc(65536);
  char* p_v    = alloc(33554432);  // v bf16 ; later aliased by a3 (h*r)
  char* p_vT   = alloc(33554432);  // vT bf16 (B,H,L)
  char* p_u    = alloc(16777216);  // u bf16 ; EMA aliases: E(8MB)+Sinit(8MB)
  char* p_r    = alloc(33554432);  // r bf16
  char* p_hx   = alloc(16777216);  // hx bf16

  float* p_E  = (float*)p_u;
  float* p_si = (float*)(p_u + 8388608);

  f2b_all<<<8320, 256, 0, stream>>>((const float4*)Wv, (const float4*)Wmx, (const float4*)Wh,
                                    (bf16x4*)p_wvb, (bf16x4*)p_wmxb, (bf16x4*)p_whb);
  ema_params_k<<<64, 256, 0, stream>>>(edelta, ealpha, ebeta, egamma,
                                       (float*)p_eq, (float*)p_ew, (float*)p_qc);
  ln_kernel<<<8192, 256, 0, stream>>>(x, lnw, lnb, (__bf16*)p_xnb);

  ema_chunk_k<<<dim3(16,EMA_NCH,4), 64, 0, stream>>>((const __bf16*)p_xnb, (const float*)p_eq, p_E);
  ema_scan_k<<<256, 256, 0, stream>>>(p_E, (const float*)p_qc, p_si);
  ema_out_k<<<dim3(16,EMA_NCH,4), 64, 0, stream>>>((const __bf16*)p_xnb, (const float*)p_eq,
                                                   (const float*)p_ew, eomega, p_si, (__bf16*)p_mx);

  // merged: [base = mx@Wmx^T -> u/(qx,kx)/r/hx] (y<33)  ||  [v = silu(xn@Wv^T+bv)] (y>=33)
  gemm_bt<1><<<dim3(64,49,1), 256, 0, stream>>>((const __bf16*)p_mx, (const __bf16*)p_wmxb,
      1024, 0, 0, bmx, p_u, p_r, p_hx, p_qx, qkg, qkb, p_kx,
      (const __bf16*)p_xnb, (const __bf16*)p_wvb, bv, p_v);

  transpose_v<<<dim3(32,32,4), 256, 0, stream>>>((const __bf16*)p_v, (__bf16*)p_vT);
  rot_fill<<<LSEQ, 128, 0, stream>>>(ralpha, rbeta, (__bf16*)p_qx, (__bf16*)p_kx);

  // S = laplace(qx @ kx^T)
  __bf16* S = (__bf16*)p_S;
  gemm_bt<2><<<dim3(16,16,4), 256, 0, stream>>>((const __bf16*)p_qx, (const __bf16*)p_kx,
      256, (long)LSEQ*NEXTD, (long)LSEQ*NEXTD, nullptr, S, nullptr, nullptr, nullptr,
      nullptr, nullptr, nullptr, nullptr, nullptr, nullptr, nullptr);

  // a3 = (S @ vT^T) * r
  __bf16* a3 = (__bf16*)p_v;
  gemm_bt<3><<<dim3(16,16,4), 256, 0, stream>>>(S, (const __bf16*)p_vT,
      2048, (long)LSEQ*LSEQ, (long)HD*LSEQ, nullptr, a3, nullptr, nullptr, nullptr,
      p_r, nullptr, nullptr, nullptr, nullptr, nullptr, nullptr);

  // out = x + u*(silu(hx + a3 @ Wh^T + bh) - x)
  gemm_bt<4><<<dim3(64,8,1), 256, 0, stream>>>(a3, (const __bf16*)p_whb,
      2048, 0, 0, bh, out, nullptr, nullptr, nullptr, p_hx, p_u, x,
      nullptr, nullptr, nullptr, nullptr);
}

// Round 6
// 619.182 us; speedup vs baseline: 1.2113x; 1.0412x over previous
//
#include <hip/hip_runtime.h>
#include <hip/hip_bf16.h>
#include <math.h>

#define LSEQ 2048
#define NB 4
#define DM 1024
#define ZD 128
#define HD 2048
#define ND 16
#define NEXTD 256
#define EMA_C 64
#define EMA_NCH 32

typedef __bf16 bf16x8 __attribute__((ext_vector_type(8)));
typedef __bf16 bf16x4 __attribute__((ext_vector_type(4)));
typedef float f32x4 __attribute__((ext_vector_type(4)));
typedef unsigned char uchar;

__device__ __forceinline__ float sigm(float x){ return 1.0f/(1.0f+expf(-x)); }
__device__ __forceinline__ float silu_(float x){ return x/(1.0f+expf(-x)); }
__device__ __forceinline__ float laplacef(float x){ return 0.5f*(1.0f+erff((x-0.70710678f)*2.5066282746f)); }

__device__ __forceinline__ void load_lds16(const __bf16* g, __bf16* l){
  __builtin_amdgcn_global_load_lds((const __attribute__((address_space(1))) void*)g,
                                   (__attribute__((address_space(3))) void*)l, 16, 0, 0);
}
__device__ __forceinline__ void load_lds16b(const uchar* g, uchar* l){
  __builtin_amdgcn_global_load_lds((const __attribute__((address_space(1))) void*)g,
                                   (__attribute__((address_space(3))) void*)l, 16, 0, 0);
}
// pack 4 f32 -> 4 fp8 e4m3 bytes (OCP on gfx950)
__device__ __forceinline__ unsigned int pk4_fp8(float a, float b, float c, float d){
  int v = __builtin_amdgcn_cvt_pk_fp8_f32(a, b, 0, false);
  v = __builtin_amdgcn_cvt_pk_fp8_f32(c, d, v, true);
  return (unsigned int)v;
}

// ---------------- all three weights fp32 -> bf16, one launch ----------------
__global__ __launch_bounds__(256) void f2b_all(const float4* __restrict__ w0, const float4* __restrict__ w1,
                                               const float4* __restrict__ w2, bf16x4* __restrict__ o0,
                                               bf16x4* __restrict__ o1, bf16x4* __restrict__ o2){
  const int i = blockIdx.x*256 + threadIdx.x;
  const int n0 = 524288, n1 = 1081344, n2 = 524288;
  const float4* src; bf16x4* dst; int k;
  if (i < n0){ src = w0; dst = o0; k = i; }
  else if (i < n0+n1){ src = w1; dst = o1; k = i-n0; }
  else if (i < n0+n1+n2){ src = w2; dst = o2; k = i-n0-n1; }
  else return;
  float4 v = src[k];
  bf16x4 o; o[0]=(__bf16)v.x; o[1]=(__bf16)v.y; o[2]=(__bf16)v.z; o[3]=(__bf16)v.w;
  dst[k] = o;
}

// ---------------- LayerNorm (bf16 out, l-major [l][b][d]) ----------------
__global__ __launch_bounds__(256) void ln_kernel(const float* __restrict__ x, const float* __restrict__ w,
                                                 const float* __restrict__ b, __bf16* __restrict__ xnb){
  const long row = blockIdx.x;
  const int tid = threadIdx.x;
  float4 v = ((const float4*)(x + row*DM))[tid];
  float s = v.x+v.y+v.z+v.w;
  float ss = v.x*v.x+v.y*v.y+v.z*v.z+v.w*v.w;
#pragma unroll
  for (int o=32;o>0;o>>=1){ s += __shfl_down(s,o); ss += __shfl_down(ss,o); }
  __shared__ float red[8];
  __shared__ float mv[2];
  const int wid2 = tid>>6, lane = tid&63;
  if (lane==0){ red[wid2]=s; red[4+wid2]=ss; }
  __syncthreads();
  if (tid==0){
    float ts = red[0]+red[1]+red[2]+red[3];
    float tss = red[4]+red[5]+red[6]+red[7];
    float mean = ts*(1.0f/DM);
    float var = tss*(1.0f/DM) - mean*mean;
    mv[0]=mean; mv[1]=rsqrtf(var + 1e-5f);
  }
  __syncthreads();
  const float mean=mv[0], rs=mv[1];
  float4 wv = ((const float4*)w)[tid];
  float4 bv = ((const float4*)b)[tid];
  bf16x4 ob;
  ob[0]=(__bf16)((v.x-mean)*rs*wv.x+bv.x);
  ob[1]=(__bf16)((v.y-mean)*rs*wv.y+bv.y);
  ob[2]=(__bf16)((v.z-mean)*rs*wv.z+bv.z);
  ob[3]=(__bf16)((v.w-mean)*rs*wv.w+bv.w);
  ((bf16x4*)(xnb + row*DM))[tid]=ob;
}

// ---------------- EMA parameter precompute ----------------
__global__ __launch_bounds__(256) void ema_params_k(const float* __restrict__ de, const float* __restrict__ al,
                                                    const float* __restrict__ be, const float* __restrict__ ga,
                                                    float* __restrict__ qo, float* __restrict__ wo,
                                                    float* __restrict__ qco){
  const int i = blockIdx.x*256 + threadIdx.x;
  const float p = sigm(de[i]);
  const float q = 1.0f - p*sigm(al[i]);
  qo[i] = q;
  wo[i] = p*be[i]*ga[i]*0.25f;
  qco[i] = powf(q, (float)EMA_C);
}

// ---------------- EMA pass A ----------------
__global__ __launch_bounds__(64) void ema_chunk_k(const __bf16* __restrict__ xn, const float* __restrict__ qp,
                                                  float* __restrict__ E){
  const int d = blockIdx.x*64 + threadIdx.x;
  const int j = blockIdx.y, b = blockIdx.z;
  float q[ND], s[ND];
#pragma unroll
  for (int n=0;n<ND;n++){ q[n]=qp[d*ND+n]; s[n]=0.0f; }
  const __bf16* xc = xn + (long)b*DM + d + (long)j*EMA_C*(NB*DM);
#pragma unroll
  for (int lt=0; lt<EMA_C; lt+=4){
    float xv[4];
#pragma unroll
    for (int u=0;u<4;u++) xv[u] = (float)xc[(long)(lt+u)*(NB*DM)];
#pragma unroll
    for (int u=0;u<4;u++)
#pragma unroll
      for (int n=0;n<ND;n++) s[n] = fmaf(q[n], s[n], xv[u]);
  }
  float4* Eo = (float4*)(E + (((long)b*EMA_NCH + j)*DM + d)*ND);
#pragma unroll
  for (int n=0;n<4;n++) Eo[n] = make_float4(s[4*n], s[4*n+1], s[4*n+2], s[4*n+3]);
}

// ---------------- EMA pass B ----------------
__global__ __launch_bounds__(256) void ema_scan_k(const float* __restrict__ E, const float* __restrict__ qc,
                                                  float* __restrict__ Sinit){
  const int t = blockIdx.x*256 + threadIdx.x;
  const int b = t >> 14;
  const int rem = t & 16383;
  const float q64 = qc[rem];
  float s = 0.0f;
  const long base = (long)b*EMA_NCH*16384 + rem;
  for (int j=0;j<EMA_NCH;j++){
    const long idx = base + (long)j*16384;
    Sinit[idx] = s;
    s = fmaf(q64, s, E[idx]);
  }
}

// ---------------- EMA pass C ----------------
__global__ __launch_bounds__(64) void ema_out_k(const __bf16* __restrict__ xn, const float* __restrict__ qp,
                                                const float* __restrict__ wp, const float* __restrict__ omega,
                                                const float* __restrict__ Sinit, __bf16* __restrict__ mx){
  const int d = blockIdx.x*64 + threadIdx.x;
  const int j = blockIdx.y, b = blockIdx.z;
  float q[ND], w[ND], s[ND];
  const float4* Si = (const float4*)(Sinit + (((long)b*EMA_NCH + j)*DM + d)*ND);
#pragma unroll
  for (int n=0;n<4;n++){ float4 v=Si[n]; s[4*n]=v.x; s[4*n+1]=v.y; s[4*n+2]=v.z; s[4*n+3]=v.w; }
#pragma unroll
  for (int n=0;n<ND;n++){ q[n]=qp[d*ND+n]; w[n]=wp[d*ND+n]; }
  const float om = omega[d];
  const int l0 = j*EMA_C;
  const __bf16* xc = xn + (long)b*DM + d;
#pragma unroll
  for (int lt=0; lt<EMA_C; lt+=4){
    float xv[4];
#pragma unroll
    for (int u=0;u<4;u++) xv[u] = (float)xc[(long)(l0+lt+u)*(NB*DM)];
#pragma unroll
    for (int u=0;u<4;u++){
      float a = 0.0f;
#pragma unroll
      for (int n=0;n<ND;n++){ s[n] = fmaf(q[n], s[n], xv[u]); a = fmaf(w[n], s[n], a); }
      mx[((long)(l0+lt+u)*NB + b)*DM + d] = (__bf16)silu_(a + xv[u]*om);
    }
  }
}

// ---------------- v (L*B,H) -> vT8 (B,H,L), fp8 x8 scale ----------------
__global__ __launch_bounds__(256) void transpose_v8(const __bf16* __restrict__ v, uchar* __restrict__ vT){
  __shared__ __bf16 t[64][65];
  const int b = blockIdx.z;
  const int l0 = blockIdx.x*64, h0 = blockIdx.y*64;
  const int tx = threadIdx.x & 63, ty = threadIdx.x >> 6;
  for (int i=ty;i<64;i+=4) t[i][tx] = v[((long)(l0+i)*NB + b)*HD + h0 + tx];
  __syncthreads();
  const int h = threadIdx.x >> 2;
  const int lq = (threadIdx.x & 3) * 16;
  float f[16];
#pragma unroll
  for (int e=0;e<16;e++) f[e] = 8.0f*(float)t[lq+e][h];
  uint4 ov;
  ov.x = pk4_fp8(f[0],f[1],f[2],f[3]);
  ov.y = pk4_fp8(f[4],f[5],f[6],f[7]);
  ov.z = pk4_fp8(f[8],f[9],f[10],f[11]);
  ov.w = pk4_fp8(f[12],f[13],f[14],f[15]);
  *(uint4*)&vT[((long)b*HD + h0 + h)*LSEQ + l0 + lq] = ov;
}

// ---------------- rotary extension cols [128,256) of qx/kx (b-major) ----------------
__global__ __launch_bounds__(128) void rot_fill(const float* __restrict__ ra, const float* __restrict__ rb,
                                                __bf16* __restrict__ qx, __bf16* __restrict__ kx){
  const int l = blockIdx.x, i = threadIdx.x;
  const int jf = i & 63;
  const float f = expf((float)jf * (-0.14391156831f));
  const float ang = (float)l * f;
  const float sn = sinf(ang), cs = cosf(ang);
  float qv, kv;
  if (i < 64){ qv = ra[i]*cs - ra[i+64]*sn; kv = rb[i]*cs - rb[i+64]*sn; }
  else       { qv = ra[i]*cs + ra[i-64]*sn; kv = rb[i]*cs + rb[i-64]*sn; }
  const __bf16 qb = (__bf16)qv, kb = (__bf16)kv;
#pragma unroll
  for (int b=0;b<NB;b++){
    const long o = ((long)b*LSEQ + l)*NEXTD + 128 + i;
    qx[o] = qb;
    kx[o] = kb;
  }
}

// ---------------- bf16 GEMM template (16x16x32 MFMA, m97 structure) ----------------
// MODE: 0=v(silu,bf16)  1=base split(u/qk/r/hx)  2=laplace*16 -> fp8 S  4=final f32
template<int MODE>
__global__ __launch_bounds__(256) void gemm_bt(
    const __bf16* __restrict__ A, const __bf16* __restrict__ Bw,
    int K, long aBatch, long bBatch, const float* __restrict__ bias,
    void* __restrict__ o0, void* __restrict__ o1, void* __restrict__ o2, void* __restrict__ o3,
    const void* __restrict__ x0, const void* __restrict__ x1, const void* __restrict__ x2)
{
  __shared__ __align__(16) char smem_raw[34816];
  __bf16* As = (__bf16*)smem_raw;
  __bf16* Bs = (__bf16*)(smem_raw + 16384);
  const int tid = threadIdx.x;
  const int lane = tid & 63;
  const int wid = tid >> 6;
  const int bz = blockIdx.z;
  const long m0 = (long)blockIdx.x * 128;
  const long n0 = (long)blockIdx.y * 128;
  const __bf16* Ab = A + (long)bz * aBatch;
  const __bf16* Bb = Bw + (long)bz * bBatch;
  const int wm = wid & 1, wn = wid >> 1;
  const int lrow = lane >> 3;
  const int gchunk = (lane & 7) ^ lrow;

  f32x4 acc[4][4];
#pragma unroll
  for (int i=0;i<4;i++)
#pragma unroll
    for (int j=0;j<4;j++)
#pragma unroll
      for (int r=0;r<4;r++) acc[i][j][r] = 0.0f;

  for (int k0=0;k0<K;k0+=64){
    __syncthreads();
#pragma unroll
    for (int j=0;j<4;j++){
      const int g = j*4 + wid;
      const long ar = m0 + g*8 + lrow;
      load_lds16(Ab + ar*(long)K + (k0 + gchunk*8), &As[g*512]);
      const long br = n0 + g*8 + lrow;
      load_lds16(Bb + br*(long)K + (k0 + gchunk*8), &Bs[g*512]);
    }
    __syncthreads();
#pragma unroll
    for (int ks=0;ks<2;ks++){
      bf16x8 af[4], bfv[4];
      const int qd = (lane>>4) + ks*4;
#pragma unroll
      for (int i=0;i<4;i++){
        const int rowa = wm*64 + i*16 + (lane&15);
        af[i]  = *(const bf16x8*)&As[rowa*64 + ((qd ^ (rowa&7))<<3)];
        const int rowb = wn*64 + i*16 + (lane&15);
        bfv[i] = *(const bf16x8*)&Bs[rowb*64 + ((qd ^ (rowb&7))<<3)];
      }
#pragma unroll
      for (int i=0;i<4;i++)
#pragma unroll
        for (int j=0;j<4;j++)
          acc[i][j] = __builtin_amdgcn_mfma_f32_16x16x32_bf16(af[i], bfv[j], acc[i][j], 0, 0, 0);
    }
  }

  // ---------------- epilogue ----------------
  __bf16* st = (__bf16*)smem_raw;      // 128 x 136 bf16
  float*  stf = (float*)smem_raw;      // 128 x 68 f32
  const int quad = lane >> 4;
  const int row = tid >> 1, half = tid & 1;
  const long row_g = m0 + row;

  if (MODE == 4){
#pragma unroll
    for (int p=0;p<2;p++){
      __syncthreads();
      if (wn == p){
#pragma unroll
        for (int i=0;i<4;i++){
          const int tr0 = wm*64 + i*16 + quad*4;
#pragma unroll
          for (int j=0;j<4;j++){
            const int tc = j*16 + (lane&15);
            const float bb = bias[n0 + p*64 + tc];
#pragma unroll
            for (int r=0;r<4;r++) stf[(tr0+r)*68 + tc] = acc[i][j][r] + bb;
          }
        }
      }
      __syncthreads();
#pragma unroll
      for (int k=0;k<8;k++){
        f32x4 c4 = *(const f32x4*)&stf[row*68 + half*32 + k*4];
        const long cg = n0 + p*64 + half*32 + k*4;
        const long idx = row_g*DM + cg;
        bf16x4 h4 = *(const bf16x4*)((const __bf16*)x0 + idx);
        bf16x4 u4 = *(const bf16x4*)((const __bf16*)x1 + idx);
        float4 xv = *(const float4*)((const float*)x2 + idx);
        float4 o;
        o.x = xv.x + (float)u4[0]*(silu_((float)h4[0]+c4[0]) - xv.x);
        o.y = xv.y + (float)u4[1]*(silu_((float)h4[1]+c4[1]) - xv.y);
        o.z = xv.z + (float)u4[2]*(silu_((float)h4[2]+c4[2]) - xv.z);
        o.w = xv.w + (float)u4[3]*(silu_((float)h4[3]+c4[3]) - xv.w);
        *(float4*)((float*)o0 + idx) = o;
      }
    }
    return;
  }

  if (MODE == 1 && n0 == DM){
    const float* qkg = (const float*)x0;
    const float* qkb = (const float*)x1;
    __bf16* qx = (__bf16*)o3;
    __bf16* kx = (__bf16*)x2;
#pragma unroll
    for (int pass=0; pass<2; pass++){
      __syncthreads();
#pragma unroll
      for (int i=0;i<4;i++){
        const int tr0 = wm*64 + i*16 + quad*4;
#pragma unroll
        for (int j=0;j<4;j++){
          const int tc = wn*64 + j*16 + (lane&15);
          const float bb = bias[DM + tc];
          const float g = pass ? qkg[ZD+tc] : qkg[tc];
          const float be = pass ? qkb[ZD+tc] : qkb[tc];
          const float sc = pass ? 1.0f : (1.0f/LSEQ);
#pragma unroll
          for (int r=0;r<4;r++){
            const float s = silu_(acc[i][j][r] + bb);
            st[(tr0+r)*136 + tc] = (__bf16)((s*g + be)*sc);
          }
        }
      }
      __syncthreads();
      __bf16* dst = pass ? kx : qx;
      const long l = row_g >> 2, b = row_g & 3;
      const long base = (b*LSEQ + l)*NEXTD;
#pragma unroll
      for (int k=0;k<8;k++){
        bf16x8 vv = *(const bf16x8*)&st[row*136 + half*64 + k*8];
        *(bf16x8*)(dst + base + half*64 + k*8) = vv;
      }
    }
    return;
  }

  // staging with per-mode transform
  __syncthreads();
#pragma unroll
  for (int i=0;i<4;i++){
    const int tr0 = wm*64 + i*16 + quad*4;
#pragma unroll
    for (int j=0;j<4;j++){
      const int tc = wn*64 + j*16 + (lane&15);
      const long col = n0 + tc;
      float bb = 0.0f;
      if (MODE==0 || MODE==1) bb = bias[col];
#pragma unroll
      for (int r=0;r<4;r++){
        float c = acc[i][j][r] + bb;
        if (MODE==0) c = silu_(c);
        else if (MODE==1){ c = (col < DM) ? sigm(c) : ((col < DM+ZD+HD) ? silu_(c) : c); }
        else if (MODE==2) c = laplacef(c)*16.0f;   // fp8 scale
        st[(tr0+r)*136 + tc] = (__bf16)c;
      }
    }
  }
  __syncthreads();

  if (MODE==2){
    // fp8 store: S8[b][l][m], value = laplace*16
    uchar* dst = (uchar*)o0;
    const long base = (long)bz*LSEQ*LSEQ + row_g*LSEQ + n0 + half*64;
#pragma unroll
    for (int k=0;k<4;k++){
      bf16x8 v0 = *(const bf16x8*)&st[row*136 + half*64 + k*16];
      bf16x8 v1 = *(const bf16x8*)&st[row*136 + half*64 + k*16 + 8];
      uint4 ov;
      ov.x = pk4_fp8((float)v0[0],(float)v0[1],(float)v0[2],(float)v0[3]);
      ov.y = pk4_fp8((float)v0[4],(float)v0[5],(float)v0[6],(float)v0[7]);
      ov.z = pk4_fp8((float)v1[0],(float)v1[1],(float)v1[2],(float)v1[3]);
      ov.w = pk4_fp8((float)v1[4],(float)v1[5],(float)v1[6],(float)v1[7]);
      *(uint4*)(dst + base + k*16) = ov;
    }
  } else {
    __bf16* dst; long ld, coff;
    if (MODE==0){ dst = (__bf16*)o0; ld = HD; coff = n0; }
    else {
      if (n0 < DM)            { dst = (__bf16*)o0; ld = DM; coff = n0; }          // u
      else if (n0 < DM+ZD+HD) { dst = (__bf16*)o1; ld = HD; coff = n0-DM-ZD; }    // r
      else                    { dst = (__bf16*)o2; ld = DM; coff = n0-DM-ZD-HD; } // hx
    }
    const long base = row_g*ld + coff + half*64;
#pragma unroll
    for (int k=0;k<8;k++){
      bf16x8 vv = *(const bf16x8*)&st[row*136 + half*64 + k*8];
      *(bf16x8*)(dst + base + k*8) = vv;
    }
  }
}

// ---------------- fp8 GEMM: a3 = (S8 @ vT8^T)/128 * r  (16x16x32 fp8 MFMA, BK=64) ----------------
// LDS rows 64 B (16 banks), even-chunk XOR swizzle: <=2-way conflicts on stage & frag reads.
__global__ __launch_bounds__(256) void gemm_fp8_att(
    const uchar* __restrict__ S8, const uchar* __restrict__ V8,
    const __bf16* __restrict__ rgate, __bf16* __restrict__ a3)
{
  __shared__ __align__(16) char smem_raw[34816];
  uchar* As = (uchar*)smem_raw;
  uchar* Bs = (uchar*)smem_raw + 8192;
  const int tid = threadIdx.x;
  const int lane = tid & 63;
  const int wid = tid >> 6;
  const int bz = blockIdx.z;
  const long m0 = (long)blockIdx.x * 128;
  const long n0 = (long)blockIdx.y * 128;
  const uchar* Ab = S8 + (long)bz * LSEQ * LSEQ;
  const uchar* Bb = V8 + (long)bz * (long)HD * LSEQ;
  const int wm = wid & 1, wn = wid >> 1;
  const int srow = lane >> 2;     // 16 rows per staging group
  const int schunk = lane & 3;    // 4 x 16B chunks per 64B row

  f32x4 acc[4][4];
#pragma unroll
  for (int i=0;i<4;i++)
#pragma unroll
    for (int j=0;j<4;j++)
#pragma unroll
      for (int r=0;r<4;r++) acc[i][j][r] = 0.0f;

  for (int k0=0;k0<LSEQ;k0+=64){
    __syncthreads();
#pragma unroll
    for (int j=0;j<2;j++){
      const int g = j*4 + wid;                 // 8 groups x 16 rows
      const int rr = g*16 + srow;
      const int gc = schunk ^ ((rr>>1)&3);
      load_lds16b(Ab + (m0+rr)*(long)LSEQ + k0 + gc*16, &As[g*1024]);
      load_lds16b(Bb + (n0+rr)*(long)LSEQ + k0 + gc*16, &Bs[g*1024]);
    }
    __syncthreads();
#pragma unroll
    for (int mi=0;mi<2;mi++){
      const int g = mi*4 + (lane>>4);          // 8B slot id (global qd)
      long af[4], bfr[4];
#pragma unroll
      for (int i=0;i<4;i++){
        const int ra = wm*64 + i*16 + (lane&15);
        af[i]  = *(const long*)&As[ra*64 + ((g ^ (ra&6))<<3)];
        const int rb = wn*64 + i*16 + (lane&15);
        bfr[i] = *(const long*)&Bs[rb*64 + ((g ^ (rb&6))<<3)];
      }
#pragma unroll
      for (int i=0;i<4;i++)
#pragma unroll
        for (int j=0;j<4;j++)
          acc[i][j] = __builtin_amdgcn_mfma_f32_16x16x32_fp8_fp8(af[i], bfr[j], acc[i][j], 0, 0, 0);
    }
  }

  // epilogue: stage bf16 (x 1/128), multiply by r, store a3 [l][b][h]
  __bf16* st = (__bf16*)smem_raw;
  const int quad = lane >> 4;
  const int row = tid >> 1, half = tid & 1;
  const long row_g = m0 + row;
  __syncthreads();
#pragma unroll
  for (int i=0;i<4;i++){
    const int tr0 = wm*64 + i*16 + quad*4;
#pragma unroll
    for (int j=0;j<4;j++){
      const int tc = wn*64 + j*16 + (lane&15);
#pragma unroll
      for (int r=0;r<4;r++)
        st[(tr0+r)*136 + tc] = (__bf16)(acc[i][j][r] * (1.0f/128.0f));
    }
  }
  __syncthreads();
  const long base = (row_g*NB + bz)*HD + n0 + half*64;
#pragma unroll
  for (int k=0;k<8;k++){
    bf16x8 vv = *(const bf16x8*)&st[row*136 + half*64 + k*8];
    bf16x8 rv = *(const bf16x8*)(rgate + base + k*8);
    bf16x8 ov;
#pragma unroll
    for (int e=0;e<8;e++) ov[e] = (__bf16)((float)vv[e]*(float)rv[e]);
    *(bf16x8*)(a3 + base + k*8) = ov;
  }
}

extern "C" void kernel_launch(void* const* d_in, const int* in_sizes, int n_in,
                              void* d_out, int out_size, void* d_ws, size_t ws_size,
                              hipStream_t stream) {
  const float* x      = (const float*)d_in[0];
  const float* edelta = (const float*)d_in[1];
  const float* ealpha = (const float*)d_in[2];
  const float* ebeta  = (const float*)d_in[3];
  const float* egamma = (const float*)d_in[4];
  const float* eomega = (const float*)d_in[5];
  const float* lnw    = (const float*)d_in[6];
  const float* lnb    = (const float*)d_in[7];
  const float* Wv     = (const float*)d_in[8];
  const float* bv     = (const float*)d_in[9];
  const float* Wmx    = (const float*)d_in[10];
  const float* bmx    = (const float*)d_in[11];
  const float* Wh     = (const float*)d_in[12];
  const float* bh     = (const float*)d_in[13];
  const float* qkg    = (const float*)d_in[14];
  const float* qkb    = (const float*)d_in[15];
  const float* ralpha = (const float*)d_in[16];
  const float* rbeta  = (const float*)d_in[17];
  float* out = (float*)d_out;

  char* ws = (char*)d_ws;
  size_t off = 0;
  auto alloc = [&](size_t bytes) -> char* {
    char* p = ws + off; off = (off + bytes + 255) & ~(size_t)255; return p;
  };
  char* p_S8   = alloc(16777216);  // S fp8 [b][l][m] (laplace*16)
  char* p_xnb  = alloc(16777216);  // xn bf16 [l][b][d]
  char* p_qx   = alloc(4194304);   // qx bf16 [b][l][256]
  char* p_kx   = alloc(4194304);   // kx bf16 [b][l][256]
  char* p_mx   = alloc(16777216);  // mx bf16 [l][b][d]
  char* p_wvb  = alloc(4194304);
  char* p_wmxb = alloc(8650752);
  char* p_whb  = alloc(4194304);
  char* p_eq   = alloc(65536);
  char* p_ew   = alloc(65536);
  char* p_qc   = alloc(65536);
  char* p_v    = alloc(33554432);  // v bf16 [l][b][h]; later aliased by a3
  char* p_vT8  = alloc(16777216);  // vT fp8 [b][h][l] (v*8)
  char* p_u    = alloc(16777216);  // u bf16 ; EMA aliases: E(8MB)+Sinit(8MB)
  char* p_r    = alloc(33554432);  // r bf16 [l][b][h]
  char* p_hx   = alloc(16777216);  // hx bf16

  float* p_E  = (float*)p_u;
  float* p_si = (float*)(p_u + 8388608);

  f2b_all<<<8320, 256, 0, stream>>>((const float4*)Wv, (const float4*)Wmx, (const float4*)Wh,
                                    (bf16x4*)p_wvb, (bf16x4*)p_wmxb, (bf16x4*)p_whb);
  ema_params_k<<<64, 256, 0, stream>>>(edelta, ealpha, ebeta, egamma,
                                       (float*)p_eq, (float*)p_ew, (float*)p_qc);
  ln_kernel<<<8192, 256, 0, stream>>>(x, lnw, lnb, (__bf16*)p_xnb);

  ema_chunk_k<<<dim3(16,EMA_NCH,4), 64, 0, stream>>>((const __bf16*)p_xnb, (const float*)p_eq, p_E);
  ema_scan_k<<<256, 256, 0, stream>>>(p_E, (const float*)p_qc, p_si);
  ema_out_k<<<dim3(16,EMA_NCH,4), 64, 0, stream>>>((const __bf16*)p_xnb, (const float*)p_eq,
                                                   (const float*)p_ew, eomega, p_si, (__bf16*)p_mx);

  // v = silu(xn @ Wv^T + bv)
  gemm_bt<0><<<dim3(64,16,1), 256, 0, stream>>>((const __bf16*)p_xnb, (const __bf16*)p_wvb,
      1024, 0, 0, bv, p_v, nullptr, nullptr, nullptr, nullptr, nullptr, nullptr);
  transpose_v8<<<dim3(32,32,4), 256, 0, stream>>>((const __bf16*)p_v, (uchar*)p_vT8);

  // base = mx @ Wmx^T + bmx -> u / (qx,kx) / r / hx
  gemm_bt<1><<<dim3(64,33,1), 256, 0, stream>>>((const __bf16*)p_mx, (const __bf16*)p_wmxb,
      1024, 0, 0, bmx, p_u, p_r, p_hx, p_qx, qkg, qkb, p_kx);
  rot_fill<<<LSEQ, 128, 0, stream>>>(ralpha, rbeta, (__bf16*)p_qx, (__bf16*)p_kx);

  // S8 = fp8(laplace(qx @ kx^T) * 16)
  gemm_bt<2><<<dim3(16,16,4), 256, 0, stream>>>((const __bf16*)p_qx, (const __bf16*)p_kx,
      256, (long)LSEQ*NEXTD, (long)LSEQ*NEXTD, nullptr, p_S8, nullptr, nullptr, nullptr,
      nullptr, nullptr, nullptr);

  // a3 = (S8 @ vT8^T)/128 * r
  __bf16* a3 = (__bf16*)p_v;
  gemm_fp8_att<<<dim3(16,16,4), 256, 0, stream>>>((const uchar*)p_S8, (const uchar*)p_vT8,
      (const __bf16*)p_r, a3);

  // out = x + u*(silu(hx + a3 @ Wh^T + bh) - x)
  gemm_bt<4><<<dim3(64,8,1), 256, 0, stream>>>(a3, (const __bf16*)p_whb,
      2048, 0, 0, bh, out, nullptr, nullptr, nullptr, p_hx, p_u, x);
}

// Round 7
// 505.828 us; speedup vs baseline: 1.4828x; 1.2241x over previous
//
#include <hip/hip_runtime.h>
#include <hip/hip_bf16.h>
#include <math.h>

#define LSEQ 2048
#define NB 4
#define DM 1024
#define ZD 128
#define HD 2048
#define ND 16
#define NEXTD 256
#define EMA_C 64
#define EMA_NCH 32

typedef __bf16 bf16x8 __attribute__((ext_vector_type(8)));
typedef __bf16 bf16x4 __attribute__((ext_vector_type(4)));
typedef float f32x4 __attribute__((ext_vector_type(4)));
typedef unsigned char uchar;

__device__ __forceinline__ float sigm(float x){ return 1.0f/(1.0f+expf(-x)); }
__device__ __forceinline__ float silu_(float x){ return x/(1.0f+expf(-x)); }
__device__ __forceinline__ float laplacef(float x){ return 0.5f*(1.0f+erff((x-0.70710678f)*2.5066282746f)); }

__device__ __forceinline__ void load_lds16(const __bf16* g, __bf16* l){
  __builtin_amdgcn_global_load_lds((const __attribute__((address_space(1))) void*)g,
                                   (__attribute__((address_space(3))) void*)l, 16, 0, 0);
}
__device__ __forceinline__ void load_lds16b(const uchar* g, uchar* l){
  __builtin_amdgcn_global_load_lds((const __attribute__((address_space(1))) void*)g,
                                   (__attribute__((address_space(3))) void*)l, 16, 0, 0);
}
// pack 4 f32 -> 4 fp8 e4m3 bytes (OCP on gfx950)
__device__ __forceinline__ unsigned int pk4_fp8(float a, float b, float c, float d){
  int v = __builtin_amdgcn_cvt_pk_fp8_f32(a, b, 0, false);
  v = __builtin_amdgcn_cvt_pk_fp8_f32(c, d, v, true);
  return (unsigned int)v;
}

// ---------------- all three weights fp32 -> bf16, one launch ----------------
__global__ __launch_bounds__(256) void f2b_all(const float4* __restrict__ w0, const float4* __restrict__ w1,
                                               const float4* __restrict__ w2, bf16x4* __restrict__ o0,
                                               bf16x4* __restrict__ o1, bf16x4* __restrict__ o2){
  const int i = blockIdx.x*256 + threadIdx.x;
  const int n0 = 524288, n1 = 1081344, n2 = 524288;
  const float4* src; bf16x4* dst; int k;
  if (i < n0){ src = w0; dst = o0; k = i; }
  else if (i < n0+n1){ src = w1; dst = o1; k = i-n0; }
  else if (i < n0+n1+n2){ src = w2; dst = o2; k = i-n0-n1; }
  else return;
  float4 v = src[k];
  bf16x4 o; o[0]=(__bf16)v.x; o[1]=(__bf16)v.y; o[2]=(__bf16)v.z; o[3]=(__bf16)v.w;
  dst[k] = o;
}

// ---------------- LayerNorm (bf16 out, l-major [l][b][d]) ----------------
__global__ __launch_bounds__(256) void ln_kernel(const float* __restrict__ x, const float* __restrict__ w,
                                                 const float* __restrict__ b, __bf16* __restrict__ xnb){
  const long row = blockIdx.x;
  const int tid = threadIdx.x;
  float4 v = ((const float4*)(x + row*DM))[tid];
  float s = v.x+v.y+v.z+v.w;
  float ss = v.x*v.x+v.y*v.y+v.z*v.z+v.w*v.w;
#pragma unroll
  for (int o=32;o>0;o>>=1){ s += __shfl_down(s,o); ss += __shfl_down(ss,o); }
  __shared__ float red[8];
  __shared__ float mv[2];
  const int wid2 = tid>>6, lane = tid&63;
  if (lane==0){ red[wid2]=s; red[4+wid2]=ss; }
  __syncthreads();
  if (tid==0){
    float ts = red[0]+red[1]+red[2]+red[3];
    float tss = red[4]+red[5]+red[6]+red[7];
    float mean = ts*(1.0f/DM);
    float var = tss*(1.0f/DM) - mean*mean;
    mv[0]=mean; mv[1]=rsqrtf(var + 1e-5f);
  }
  __syncthreads();
  const float mean=mv[0], rs=mv[1];
  float4 wv = ((const float4*)w)[tid];
  float4 bv = ((const float4*)b)[tid];
  bf16x4 ob;
  ob[0]=(__bf16)((v.x-mean)*rs*wv.x+bv.x);
  ob[1]=(__bf16)((v.y-mean)*rs*wv.y+bv.y);
  ob[2]=(__bf16)((v.z-mean)*rs*wv.z+bv.z);
  ob[3]=(__bf16)((v.w-mean)*rs*wv.w+bv.w);
  ((bf16x4*)(xnb + row*DM))[tid]=ob;
}

// ---------------- EMA parameter precompute ----------------
__global__ __launch_bounds__(256) void ema_params_k(const float* __restrict__ de, const float* __restrict__ al,
                                                    const float* __restrict__ be, const float* __restrict__ ga,
                                                    float* __restrict__ qo, float* __restrict__ wo,
                                                    float* __restrict__ qco){
  const int i = blockIdx.x*256 + threadIdx.x;
  const float p = sigm(de[i]);
  const float q = 1.0f - p*sigm(al[i]);
  qo[i] = q;
  wo[i] = p*be[i]*ga[i]*0.25f;
  qco[i] = powf(q, (float)EMA_C);
}

// ---------------- EMA pass A ----------------
__global__ __launch_bounds__(64) void ema_chunk_k(const __bf16* __restrict__ xn, const float* __restrict__ qp,
                                                  float* __restrict__ E){
  const int d = blockIdx.x*64 + threadIdx.x;
  const int j = blockIdx.y, b = blockIdx.z;
  float q[ND], s[ND];
#pragma unroll
  for (int n=0;n<ND;n++){ q[n]=qp[d*ND+n]; s[n]=0.0f; }
  const __bf16* xc = xn + (long)b*DM + d + (long)j*EMA_C*(NB*DM);
#pragma unroll
  for (int lt=0; lt<EMA_C; lt+=4){
    float xv[4];
#pragma unroll
    for (int u=0;u<4;u++) xv[u] = (float)xc[(long)(lt+u)*(NB*DM)];
#pragma unroll
    for (int u=0;u<4;u++)
#pragma unroll
      for (int n=0;n<ND;n++) s[n] = fmaf(q[n], s[n], xv[u]);
  }
  float4* Eo = (float4*)(E + (((long)b*EMA_NCH + j)*DM + d)*ND);
#pragma unroll
  for (int n=0;n<4;n++) Eo[n] = make_float4(s[4*n], s[4*n+1], s[4*n+2], s[4*n+3]);
}

// ---------------- EMA pass B ----------------
__global__ __launch_bounds__(256) void ema_scan_k(const float* __restrict__ E, const float* __restrict__ qc,
                                                  float* __restrict__ Sinit){
  const int t = blockIdx.x*256 + threadIdx.x;
  const int b = t >> 14;
  const int rem = t & 16383;
  const float q64 = qc[rem];
  float s = 0.0f;
  const long base = (long)b*EMA_NCH*16384 + rem;
  for (int j=0;j<EMA_NCH;j++){
    const long idx = base + (long)j*16384;
    Sinit[idx] = s;
    s = fmaf(q64, s, E[idx]);
  }
}

// ---------------- EMA pass C ----------------
__global__ __launch_bounds__(64) void ema_out_k(const __bf16* __restrict__ xn, const float* __restrict__ qp,
                                                const float* __restrict__ wp, const float* __restrict__ omega,
                                                const float* __restrict__ Sinit, __bf16* __restrict__ mx){
  const int d = blockIdx.x*64 + threadIdx.x;
  const int j = blockIdx.y, b = blockIdx.z;
  float q[ND], w[ND], s[ND];
  const float4* Si = (const float4*)(Sinit + (((long)b*EMA_NCH + j)*DM + d)*ND);
#pragma unroll
  for (int n=0;n<4;n++){ float4 v=Si[n]; s[4*n]=v.x; s[4*n+1]=v.y; s[4*n+2]=v.z; s[4*n+3]=v.w; }
#pragma unroll
  for (int n=0;n<ND;n++){ q[n]=qp[d*ND+n]; w[n]=wp[d*ND+n]; }
  const float om = omega[d];
  const int l0 = j*EMA_C;
  const __bf16* xc = xn + (long)b*DM + d;
#pragma unroll
  for (int lt=0; lt<EMA_C; lt+=4){
    float xv[4];
#pragma unroll
    for (int u=0;u<4;u++) xv[u] = (float)xc[(long)(l0+lt+u)*(NB*DM)];
#pragma unroll
    for (int u=0;u<4;u++){
      float a = 0.0f;
#pragma unroll
      for (int n=0;n<ND;n++){ s[n] = fmaf(q[n], s[n], xv[u]); a = fmaf(w[n], s[n], a); }
      mx[((long)(l0+lt+u)*NB + b)*DM + d] = (__bf16)silu_(a + xv[u]*om);
    }
  }
}

// ---------------- v (L*B,H) -> vT8 (B,H,L), fp8 x8 scale ----------------
__global__ __launch_bounds__(256) void transpose_v8(const __bf16* __restrict__ v, uchar* __restrict__ vT){
  __shared__ __bf16 t[64][65];
  const int b = blockIdx.z;
  const int l0 = blockIdx.x*64, h0 = blockIdx.y*64;
  const int tx = threadIdx.x & 63, ty = threadIdx.x >> 6;
  for (int i=ty;i<64;i+=4) t[i][tx] = v[((long)(l0+i)*NB + b)*HD + h0 + tx];
  __syncthreads();
  const int h = threadIdx.x >> 2;
  const int lq = (threadIdx.x & 3) * 16;
  float f[16];
#pragma unroll
  for (int e=0;e<16;e++) f[e] = 8.0f*(float)t[lq+e][h];
  uint4 ov;
  ov.x = pk4_fp8(f[0],f[1],f[2],f[3]);
  ov.y = pk4_fp8(f[4],f[5],f[6],f[7]);
  ov.z = pk4_fp8(f[8],f[9],f[10],f[11]);
  ov.w = pk4_fp8(f[12],f[13],f[14],f[15]);
  *(uint4*)&vT[((long)b*HD + h0 + h)*LSEQ + l0 + lq] = ov;
}

// ---------------- rotary extension cols [128,256) of qx/kx (b-major) ----------------
__global__ __launch_bounds__(128) void rot_fill(const float* __restrict__ ra, const float* __restrict__ rb,
                                                __bf16* __restrict__ qx, __bf16* __restrict__ kx){
  const int l = blockIdx.x, i = threadIdx.x;
  const int jf = i & 63;
  const float f = expf((float)jf * (-0.14391156831f));
  const float ang = (float)l * f;
  const float sn = sinf(ang), cs = cosf(ang);
  float qv, kv;
  if (i < 64){ qv = ra[i]*cs - ra[i+64]*sn; kv = rb[i]*cs - rb[i+64]*sn; }
  else       { qv = ra[i]*cs + ra[i-64]*sn; kv = rb[i]*cs + rb[i-64]*sn; }
  const __bf16 qb = (__bf16)qv, kb = (__bf16)kv;
#pragma unroll
  for (int b=0;b<NB;b++){
    const long o = ((long)b*LSEQ + l)*NEXTD + 128 + i;
    qx[o] = qb;
    kx[o] = kb;
  }
}

// ---------------- bf16 GEMM template (16x16x32 MFMA, m97 structure) ----------------
// __launch_bounds__(256,4): force <=128 VGPR/wave -> 4 blocks/CU residency.
// MODE: 0=v(silu,bf16)  1=base split(u/qk/r/hx)  2=laplace*16 -> fp8 S  4=final f32
template<int MODE>
__global__ __launch_bounds__(256, 4) void gemm_bt(
    const __bf16* __restrict__ A, const __bf16* __restrict__ Bw,
    int K, long aBatch, long bBatch, const float* __restrict__ bias,
    void* __restrict__ o0, void* __restrict__ o1, void* __restrict__ o2, void* __restrict__ o3,
    const void* __restrict__ x0, const void* __restrict__ x1, const void* __restrict__ x2)
{
  __shared__ __align__(16) char smem_raw[34816];
  __bf16* As = (__bf16*)smem_raw;
  __bf16* Bs = (__bf16*)(smem_raw + 16384);
  const int tid = threadIdx.x;
  const int lane = tid & 63;
  const int wid = tid >> 6;
  const int bz = blockIdx.z;
  const long m0 = (long)blockIdx.x * 128;
  const long n0 = (long)blockIdx.y * 128;
  const __bf16* Ab = A + (long)bz * aBatch;
  const __bf16* Bb = Bw + (long)bz * bBatch;
  const int wm = wid & 1, wn = wid >> 1;
  const int lrow = lane >> 3;
  const int gchunk = (lane & 7) ^ lrow;

  f32x4 acc[4][4];
#pragma unroll
  for (int i=0;i<4;i++)
#pragma unroll
    for (int j=0;j<4;j++)
#pragma unroll
      for (int r=0;r<4;r++) acc[i][j][r] = 0.0f;

  for (int k0=0;k0<K;k0+=64){
    __syncthreads();
#pragma unroll
    for (int j=0;j<4;j++){
      const int g = j*4 + wid;
      const long ar = m0 + g*8 + lrow;
      load_lds16(Ab + ar*(long)K + (k0 + gchunk*8), &As[g*512]);
      const long br = n0 + g*8 + lrow;
      load_lds16(Bb + br*(long)K + (k0 + gchunk*8), &Bs[g*512]);
    }
    __syncthreads();
#pragma unroll
    for (int ks=0;ks<2;ks++){
      bf16x8 af[4], bfv[4];
      const int qd = (lane>>4) + ks*4;
#pragma unroll
      for (int i=0;i<4;i++){
        const int rowa = wm*64 + i*16 + (lane&15);
        af[i]  = *(const bf16x8*)&As[rowa*64 + ((qd ^ (rowa&7))<<3)];
        const int rowb = wn*64 + i*16 + (lane&15);
        bfv[i] = *(const bf16x8*)&Bs[rowb*64 + ((qd ^ (rowb&7))<<3)];
      }
#pragma unroll
      for (int i=0;i<4;i++)
#pragma unroll
        for (int j=0;j<4;j++)
          acc[i][j] = __builtin_amdgcn_mfma_f32_16x16x32_bf16(af[i], bfv[j], acc[i][j], 0, 0, 0);
    }
  }

  // ---------------- epilogue ----------------
  __bf16* st = (__bf16*)smem_raw;      // 128 x 136 bf16
  float*  stf = (float*)smem_raw;      // 128 x 68 f32
  const int quad = lane >> 4;
  const int row = tid >> 1, half = tid & 1;
  const long row_g = m0 + row;

  if (MODE == 4){
#pragma unroll
    for (int p=0;p<2;p++){
      __syncthreads();
      if (wn == p){
#pragma unroll
        for (int i=0;i<4;i++){
          const int tr0 = wm*64 + i*16 + quad*4;
#pragma unroll
          for (int j=0;j<4;j++){
            const int tc = j*16 + (lane&15);
            const float bb = bias[n0 + p*64 + tc];
#pragma unroll
            for (int r=0;r<4;r++) stf[(tr0+r)*68 + tc] = acc[i][j][r] + bb;
          }
        }
      }
      __syncthreads();
#pragma unroll
      for (int k=0;k<8;k++){
        f32x4 c4 = *(const f32x4*)&stf[row*68 + half*32 + k*4];
        const long cg = n0 + p*64 + half*32 + k*4;
        const long idx = row_g*DM + cg;
        bf16x4 h4 = *(const bf16x4*)((const __bf16*)x0 + idx);
        bf16x4 u4 = *(const bf16x4*)((const __bf16*)x1 + idx);
        float4 xv = *(const float4*)((const float*)x2 + idx);
        float4 o;
        o.x = xv.x + (float)u4[0]*(silu_((float)h4[0]+c4[0]) - xv.x);
        o.y = xv.y + (float)u4[1]*(silu_((float)h4[1]+c4[1]) - xv.y);
        o.z = xv.z + (float)u4[2]*(silu_((float)h4[2]+c4[2]) - xv.z);
        o.w = xv.w + (float)u4[3]*(silu_((float)h4[3]+c4[3]) - xv.w);
        *(float4*)((float*)o0 + idx) = o;
      }
    }
    return;
  }

  if (MODE == 1 && n0 == DM){
    const float* qkg = (const float*)x0;
    const float* qkb = (const float*)x1;
    __bf16* qx = (__bf16*)o3;
    __bf16* kx = (__bf16*)x2;
#pragma unroll
    for (int pass=0; pass<2; pass++){
      __syncthreads();
#pragma unroll
      for (int i=0;i<4;i++){
        const int tr0 = wm*64 + i*16 + quad*4;
#pragma unroll
        for (int j=0;j<4;j++){
          const int tc = wn*64 + j*16 + (lane&15);
          const float bb = bias[DM + tc];
          const float g = pass ? qkg[ZD+tc] : qkg[tc];
          const float be = pass ? qkb[ZD+tc] : qkb[tc];
          const float sc = pass ? 1.0f : (1.0f/LSEQ);
#pragma unroll
          for (int r=0;r<4;r++){
            const float s = silu_(acc[i][j][r] + bb);
            st[(tr0+r)*136 + tc] = (__bf16)((s*g + be)*sc);
          }
        }
      }
      __syncthreads();
      __bf16* dst = pass ? kx : qx;
      const long l = row_g >> 2, b = row_g & 3;
      const long base = (b*LSEQ + l)*NEXTD;
#pragma unroll
      for (int k=0;k<8;k++){
        bf16x8 vv = *(const bf16x8*)&st[row*136 + half*64 + k*8];
        *(bf16x8*)(dst + base + half*64 + k*8) = vv;
      }
    }
    return;
  }

  // staging with per-mode transform
  __syncthreads();
#pragma unroll
  for (int i=0;i<4;i++){
    const int tr0 = wm*64 + i*16 + quad*4;
#pragma unroll
    for (int j=0;j<4;j++){
      const int tc = wn*64 + j*16 + (lane&15);
      const long col = n0 + tc;
      float bb = 0.0f;
      if (MODE==0 || MODE==1) bb = bias[col];
#pragma unroll
      for (int r=0;r<4;r++){
        float c = acc[i][j][r] + bb;
        if (MODE==0) c = silu_(c);
        else if (MODE==1){ c = (col < DM) ? sigm(c) : ((col < DM+ZD+HD) ? silu_(c) : c); }
        else if (MODE==2) c = laplacef(c)*16.0f;   // fp8 scale
        st[(tr0+r)*136 + tc] = (__bf16)c;
      }
    }
  }
  __syncthreads();

  if (MODE==2){
    // fp8 store: S8[b][l][m], value = laplace*16
    uchar* dst = (uchar*)o0;
    const long base = (long)bz*LSEQ*LSEQ + row_g*LSEQ + n0 + half*64;
#pragma unroll
    for (int k=0;k<4;k++){
      bf16x8 v0 = *(const bf16x8*)&st[row*136 + half*64 + k*16];
      bf16x8 v1 = *(const bf16x8*)&st[row*136 + half*64 + k*16 + 8];
      uint4 ov;
      ov.x = pk4_fp8((float)v0[0],(float)v0[1],(float)v0[2],(float)v0[3]);
      ov.y = pk4_fp8((float)v0[4],(float)v0[5],(float)v0[6],(float)v0[7]);
      ov.z = pk4_fp8((float)v1[0],(float)v1[1],(float)v1[2],(float)v1[3]);
      ov.w = pk4_fp8((float)v1[4],(float)v1[5],(float)v1[6],(float)v1[7]);
      *(uint4*)(dst + base + k*16) = ov;
    }
  } else {
    __bf16* dst; long ld, coff;
    if (MODE==0){ dst = (__bf16*)o0; ld = HD; coff = n0; }
    else {
      if (n0 < DM)            { dst = (__bf16*)o0; ld = DM; coff = n0; }          // u
      else if (n0 < DM+ZD+HD) { dst = (__bf16*)o1; ld = HD; coff = n0-DM-ZD; }    // r
      else                    { dst = (__bf16*)o2; ld = DM; coff = n0-DM-ZD-HD; } // hx
    }
    const long base = row_g*ld + coff + half*64;
#pragma unroll
    for (int k=0;k<8;k++){
      bf16x8 vv = *(const bf16x8*)&st[row*136 + half*64 + k*8];
      *(bf16x8*)(dst + base + k*8) = vv;
    }
  }
}

// ---------------- fp8 GEMM: a3 = (S8 @ vT8^T)/128 * r ----------------
__global__ __launch_bounds__(256, 4) void gemm_fp8_att(
    const uchar* __restrict__ S8, const uchar* __restrict__ V8,
    const __bf16* __restrict__ rgate, __bf16* __restrict__ a3)
{
  __shared__ __align__(16) char smem_raw[34816];
  uchar* As = (uchar*)smem_raw;
  uchar* Bs = (uchar*)smem_raw + 8192;
  const int tid = threadIdx.x;
  const int lane = tid & 63;
  const int wid = tid >> 6;
  const int bz = blockIdx.z;
  const long m0 = (long)blockIdx.x * 128;
  const long n0 = (long)blockIdx.y * 128;
  const uchar* Ab = S8 + (long)bz * LSEQ * LSEQ;
  const uchar* Bb = V8 + (long)bz * (long)HD * LSEQ;
  const int wm = wid & 1, wn = wid >> 1;
  const int srow = lane >> 2;
  const int schunk = lane & 3;

  f32x4 acc[4][4];
#pragma unroll
  for (int i=0;i<4;i++)
#pragma unroll
    for (int j=0;j<4;j++)
#pragma unroll
      for (int r=0;r<4;r++) acc[i][j][r] = 0.0f;

  for (int k0=0;k0<LSEQ;k0+=64){
    __syncthreads();
#pragma unroll
    for (int j=0;j<2;j++){
      const int g = j*4 + wid;
      const int rr = g*16 + srow;
      const int gc = schunk ^ ((rr>>1)&3);
      load_lds16b(Ab + (m0+rr)*(long)LSEQ + k0 + gc*16, &As[g*1024]);
      load_lds16b(Bb + (n0+rr)*(long)LSEQ + k0 + gc*16, &Bs[g*1024]);
    }
    __syncthreads();
#pragma unroll
    for (int mi=0;mi<2;mi++){
      const int g = mi*4 + (lane>>4);
      long af[4], bfr[4];
#pragma unroll
      for (int i=0;i<4;i++){
        const int ra = wm*64 + i*16 + (lane&15);
        af[i]  = *(const long*)&As[ra*64 + ((g ^ (ra&6))<<3)];
        const int rb = wn*64 + i*16 + (lane&15);
        bfr[i] = *(const long*)&Bs[rb*64 + ((g ^ (rb&6))<<3)];
      }
#pragma unroll
      for (int i=0;i<4;i++)
#pragma unroll
        for (int j=0;j<4;j++)
          acc[i][j] = __builtin_amdgcn_mfma_f32_16x16x32_fp8_fp8(af[i], bfr[j], acc[i][j], 0, 0, 0);
    }
  }

  __bf16* st = (__bf16*)smem_raw;
  const int quad = lane >> 4;
  const int row = tid >> 1, half = tid & 1;
  const long row_g = m0 + row;
  __syncthreads();
#pragma unroll
  for (int i=0;i<4;i++){
    const int tr0 = wm*64 + i*16 + quad*4;
#pragma unroll
    for (int j=0;j<4;j++){
      const int tc = wn*64 + j*16 + (lane&15);
#pragma unroll
      for (int r=0;r<4;r++)
        st[(tr0+r)*136 + tc] = (__bf16)(acc[i][j][r] * (1.0f/128.0f));
    }
  }
  __syncthreads();
  const long base = (row_g*NB + bz)*HD + n0 + half*64;
#pragma unroll
  for (int k=0;k<8;k++){
    bf16x8 vv = *(const bf16x8*)&st[row*136 + half*64 + k*8];
    bf16x8 rv = *(const bf16x8*)(rgate + base + k*8);
    bf16x8 ov;
#pragma unroll
    for (int e=0;e<8;e++) ov[e] = (__bf16)((float)vv[e]*(float)rv[e]);
    *(bf16x8*)(a3 + base + k*8) = ov;
  }
}

extern "C" void kernel_launch(void* const* d_in, const int* in_sizes, int n_in,
                              void* d_out, int out_size, void* d_ws, size_t ws_size,
                              hipStream_t stream) {
  const float* x      = (const float*)d_in[0];
  const float* edelta = (const float*)d_in[1];
  const float* ealpha = (const float*)d_in[2];
  const float* ebeta  = (const float*)d_in[3];
  const float* egamma = (const float*)d_in[4];
  const float* eomega = (const float*)d_in[5];
  const float* lnw    = (const float*)d_in[6];
  const float* lnb    = (const float*)d_in[7];
  const float* Wv     = (const float*)d_in[8];
  const float* bv     = (const float*)d_in[9];
  const float* Wmx    = (const float*)d_in[10];
  const float* bmx    = (const float*)d_in[11];
  const float* Wh     = (const float*)d_in[12];
  const float* bh     = (const float*)d_in[13];
  const float* qkg    = (const float*)d_in[14];
  const float* qkb    = (const float*)d_in[15];
  const float* ralpha = (const float*)d_in[16];
  const float* rbeta  = (const float*)d_in[17];
  float* out = (float*)d_out;

  char* ws = (char*)d_ws;
  size_t off = 0;
  auto alloc = [&](size_t bytes) -> char* {
    char* p = ws + off; off = (off + bytes + 255) & ~(size_t)255; return p;
  };
  char* p_S8   = alloc(16777216);  // S fp8 [b][l][m] (laplace*16)
  char* p_xnb  = alloc(16777216);  // xn bf16 [l][b][d]
  char* p_qx   = alloc(4194304);   // qx bf16 [b][l][256]
  char* p_kx   = alloc(4194304);   // kx bf16 [b][l][256]
  char* p_mx   = alloc(16777216);  // mx bf16 [l][b][d]
  char* p_wvb  = alloc(4194304);
  char* p_wmxb = alloc(8650752);
  char* p_whb  = alloc(4194304);
  char* p_eq   = alloc(65536);
  char* p_ew   = alloc(65536);
  char* p_qc   = alloc(65536);
  char* p_v    = alloc(33554432);  // v bf16 [l][b][h]; later aliased by a3
  char* p_vT8  = alloc(16777216);  // vT fp8 [b][h][l] (v*8)
  char* p_u    = alloc(16777216);  // u bf16 ; EMA aliases: E(8MB)+Sinit(8MB)
  char* p_r    = alloc(33554432);  // r bf16 [l][b][h]
  char* p_hx   = alloc(16777216);  // hx bf16

  float* p_E  = (float*)p_u;
  float* p_si = (float*)(p_u + 8388608);

  f2b_all<<<8320, 256, 0, stream>>>((const float4*)Wv, (const float4*)Wmx, (const float4*)Wh,
                                    (bf16x4*)p_wvb, (bf16x4*)p_wmxb, (bf16x4*)p_whb);
  ema_params_k<<<64, 256, 0, stream>>>(edelta, ealpha, ebeta, egamma,
                                       (float*)p_eq, (float*)p_ew, (float*)p_qc);
  ln_kernel<<<8192, 256, 0, stream>>>(x, lnw, lnb, (__bf16*)p_xnb);

  ema_chunk_k<<<dim3(16,EMA_NCH,4), 64, 0, stream>>>((const __bf16*)p_xnb, (const float*)p_eq, p_E);
  ema_scan_k<<<256, 256, 0, stream>>>(p_E, (const float*)p_qc, p_si);
  ema_out_k<<<dim3(16,EMA_NCH,4), 64, 0, stream>>>((const __bf16*)p_xnb, (const float*)p_eq,
                                                   (const float*)p_ew, eomega, p_si, (__bf16*)p_mx);

  // v = silu(xn @ Wv^T + bv)
  gemm_bt<0><<<dim3(64,16,1), 256, 0, stream>>>((const __bf16*)p_xnb, (const __bf16*)p_wvb,
      1024, 0, 0, bv, p_v, nullptr, nullptr, nullptr, nullptr, nullptr, nullptr);
  transpose_v8<<<dim3(32,32,4), 256, 0, stream>>>((const __bf16*)p_v, (uchar*)p_vT8);

  // base = mx @ Wmx^T + bmx -> u / (qx,kx) / r / hx
  gemm_bt<1><<<dim3(64,33,1), 256, 0, stream>>>((const __bf16*)p_mx, (const __bf16*)p_wmxb,
      1024, 0, 0, bmx, p_u, p_r, p_hx, p_qx, qkg, qkb, p_kx);
  rot_fill<<<LSEQ, 128, 0, stream>>>(ralpha, rbeta, (__bf16*)p_qx, (__bf16*)p_kx);

  // S8 = fp8(laplace(qx @ kx^T) * 16)
  gemm_bt<2><<<dim3(16,16,4), 256, 0, stream>>>((const __bf16*)p_qx, (const __bf16*)p_kx,
      256, (long)LSEQ*NEXTD, (long)LSEQ*NEXTD, nullptr, p_S8, nullptr, nullptr, nullptr,
      nullptr, nullptr, nullptr);

  // a3 = (S8 @ vT8^T)/128 * r
  __bf16* a3 = (__bf16*)p_v;
  gemm_fp8_att<<<dim3(16,16,4), 256, 0, stream>>>((const uchar*)p_S8, (const uchar*)p_vT8,
      (const __bf16*)p_r, a3);

  // out = x + u*(silu(hx + a3 @ Wh^T + bh) - x)
  gemm_bt<4><<<dim3(64,8,1), 256, 0, stream>>>(a3, (const __bf16*)p_whb,
      2048, 0, 0, bh, out, nullptr, nullptr, nullptr, p_hx, p_u, x);
}